// Round 8
// baseline (1403.493 us; speedup 1.0000x reference)
//
#include <hip/hip_runtime.h>
#include <hip/hip_bf16.h>

#define BB 32
#define NN 32768
#define GG 64
#define KK 32
#define DD 384
#define EPSF 1e-5f

__device__ __forceinline__ float rn_add(float a, float b){ return __fadd_rn(a,b); }
__device__ __forceinline__ float rn_sub(float a, float b){ return __fsub_rn(a,b); }
__device__ __forceinline__ float rn_mul(float a, float b){ return __fmul_rn(a,b); }

// monotone float->u32 map: preserves total order of finite floats
__device__ __forceinline__ unsigned fkey(float d){
  unsigned u = __float_as_uint(d);
  return (u & 0x80000000u) ? ~u : (u | 0x80000000u);
}

#define REP32(X) X(0) X(1) X(2) X(3) X(4) X(5) X(6) X(7) \
                 X(8) X(9) X(10) X(11) X(12) X(13) X(14) X(15) \
                 X(16) X(17) X(18) X(19) X(20) X(21) X(22) X(23) \
                 X(24) X(25) X(26) X(27) X(28) X(29) X(30) X(31)
#define REP8_0(X) X(0) X(1) X(2) X(3) X(4) X(5) X(6) X(7)
#define REP8_1(X) X(8) X(9) X(10) X(11) X(12) X(13) X(14) X(15)
#define REP8_2(X) X(16) X(17) X(18) X(19) X(20) X(21) X(22) X(23)
#define REP8_3(X) X(24) X(25) X(26) X(27) X(28) X(29) X(30) X(31)

// ---- module-scope scratch: avoids any assumption about ws_size ------------
__device__ float g_center[BB*GG*3];     // 24 KB
__device__ int   g_knn[BB*GG*KK];       // 256 KB
__device__ float g_w1t[6*64];           // folded, transposed weights
__device__ float g_b1[64];
__device__ float g_w2t[64*128];
__device__ float g_b2[128];
__device__ float g_w3t[128*384];
__device__ float g_b3[384];
__device__ float g_X[BB*NN];            // 4 MB SoA coords (bit-exact copies)
__device__ float g_Y[BB*NN];            // 4 MB
__device__ float g_Z[BB*NN];            // 4 MB

// ---------------------------------------------------------------------------
// One-shot AoS -> SoA repack (bit-exact copy).
// ---------------------------------------------------------------------------
__global__ __launch_bounds__(256) void k_soa(const float* __restrict__ xyz){
  int tid = blockIdx.x * blockDim.x + threadIdx.x;   // 0 .. BB*NN-1
  int b = tid >> 15;                                  // NN = 2^15
  int p = tid & (NN - 1);
  const float* s = xyz + (size_t)b*NN*3 + (size_t)p*3;
  g_X[tid] = s[0];
  g_Y[tid] = s[1];
  g_Z[tid] = s[2];
}

// ---------------------------------------------------------------------------
// Weight prep: fold BN (scale,shift) into transposed weights.
// ---------------------------------------------------------------------------
__global__ void k_prep(const float* __restrict__ w1, const float* __restrict__ g1, const float* __restrict__ b1, const float* __restrict__ m1, const float* __restrict__ v1,
                       const float* __restrict__ w2, const float* __restrict__ g2, const float* __restrict__ b2, const float* __restrict__ m2, const float* __restrict__ v2,
                       const float* __restrict__ w3, const float* __restrict__ g3, const float* __restrict__ b3, const float* __restrict__ m3, const float* __restrict__ v3){
  int tid = blockIdx.x * blockDim.x + threadIdx.x;
  int nt  = gridDim.x * blockDim.x;
  for (int e = tid; e < 64*6; e += nt){
    int c = e >> 6, o = e & 63;
    float s = g1[o] * rsqrtf(v1[o] + EPSF);
    g_w1t[e] = w1[o*6 + c] * s;
  }
  for (int o = tid; o < 64; o += nt){
    float s = g1[o] * rsqrtf(v1[o] + EPSF);
    g_b1[o] = b1[o] - m1[o]*s;
  }
  for (int e = tid; e < 64*128; e += nt){
    int c = e >> 7, o = e & 127;
    float s = g2[o] * rsqrtf(v2[o] + EPSF);
    g_w2t[e] = w2[o*64 + c] * s;
  }
  for (int o = tid; o < 128; o += nt){
    float s = g2[o] * rsqrtf(v2[o] + EPSF);
    g_b2[o] = b2[o] - m2[o]*s;
  }
  for (int e = tid; e < 384*128; e += nt){   // e = o*128+c (input-major)
    int o = e >> 7, c = e & 127;
    float s = g3[o] * rsqrtf(v3[o] + EPSF);
    g_w3t[c*384 + o] = w3[e] * s;
  }
  for (int o = tid; o < 384; o += nt){
    float s = g3[o] * rsqrtf(v3[o] + EPSF);
    g_b3[o] = b3[o] - m3[o]*s;
  }
}

// ---------------------------------------------------------------------------
// FPS v3. r5-r7: 96 per-thread floats always spilled (allocator pins 64 VGPR
// for this kernel; launch_bounds/waves_per_eu/named-scalars all no-ops).
// Restructure so 64 VGPRs SUFFICE: only dd0..dd31 lives in registers; z in
// LDS; x,y RE-READ each iteration from SoA g_X/g_Y - lane ln reads
// X[t + i*1024]: 64 consecutive floats per wave = perfectly coalesced
// 256B L2-hit loads (384KB/block working set, L2-resident).
// Arithmetic, order, tie-breaks bit-identical to validated r3 version.
// ---------------------------------------------------------------------------
__global__ __launch_bounds__(1024)
void k_fps(const float* __restrict__ xyz,
           float* __restrict__ outCenter){
  const int b = blockIdx.x;
  const int t = threadIdx.x;
  const float* xb = xyz + (size_t)b*NN*3;
  const float* Xb = g_X + (size_t)b*NN;
  const float* Yb = g_Y + (size_t)b*NN;
  const float* Zb = g_Z + (size_t)b*NN;

  __shared__ float sz[NN];          // 128 KiB: z coords
  __shared__ float sval[16];
  __shared__ int   sidx[16];
  __shared__ int   sfar;

#define FPS_DECL(i) float dd##i = 1e10f;
  REP32(FPS_DECL)
#undef FPS_DECL
  #pragma unroll
  for (int i = 0; i < 32; ++i){ int p = t + (i << 10); sz[p] = Zb[p]; }
  __syncthreads();

  int far = 0;
  for (int it = 0; ; ++it){
    float cx = xb[far*3 + 0], cy = xb[far*3 + 1], cz = xb[far*3 + 2];
    if (t == 0){
      float* cw = g_center  + (size_t)(b*GG + it)*3;
      float* co = outCenter + (size_t)(b*GG + it)*3;
      cw[0] = cx; cw[1] = cy; cw[2] = cz;
      co[0] = cx; co[1] = cy; co[2] = cz;
    }
    if (it == GG - 1) break;

    float bv = -1.0f; int bi = 0x7fffffff;
    // slots processed in ascending i => ascending point idx => strict >
    // keeps the FIRST (lowest-index) max, matching numpy argmax.
#define FPS_LOAD(i) float xx##i = Xb[t + (i << 10)]; float yy##i = Yb[t + (i << 10)];
#define FPS_CMP(i) { \
    float dx = rn_sub(xx##i, cx); \
    float dy = rn_sub(yy##i, cy); \
    float dz = rn_sub(sz[t + (i << 10)], cz); \
    float s_ = rn_add(rn_add(rn_mul(dx,dx), rn_mul(dy,dy)), rn_mul(dz,dz)); \
    float d_ = fminf(dd##i, s_); \
    dd##i = d_; \
    if (d_ > bv){ bv = d_; bi = t + (i << 10); } }
    REP8_0(FPS_LOAD) REP8_0(FPS_CMP)
    REP8_1(FPS_LOAD) REP8_1(FPS_CMP)
    REP8_2(FPS_LOAD) REP8_2(FPS_CMP)
    REP8_3(FPS_LOAD) REP8_3(FPS_CMP)
#undef FPS_LOAD
#undef FPS_CMP

    #pragma unroll
    for (int off = 32; off >= 1; off >>= 1){
      float ov = __shfl_xor(bv, off);
      int   oi = __shfl_xor(bi, off);
      if (ov > bv || (ov == bv && oi < bi)){ bv = ov; bi = oi; }
    }
    if ((t & 63) == 0){ sval[t >> 6] = bv; sidx[t >> 6] = bi; }
    __syncthreads();
    if (t == 0){
      float v = sval[0]; int ix = sidx[0];
      #pragma unroll
      for (int w = 1; w < 16; ++w){
        float ov = sval[w]; int oi = sidx[w];
        if (ov > v || (ov == v && oi < ix)){ v = ov; ix = oi; }
      }
      sfar = ix;
    }
    __syncthreads();
    far = sfar;
  }
}

// ---------------------------------------------------------------------------
// KNN v3, exact, threshold-based (validated r5); loads switched to SoA:
// for fixed slot s, lanes read 64 consecutive floats = coalesced.
// ---------------------------------------------------------------------------
__global__ __launch_bounds__(1024) void k_knn(void){
  const int bg = blockIdx.x;        // b*64+g
  const int b  = bg >> 6;
  const int t  = threadIdx.x;       // 0..1023
  const int w  = t >> 6;            // wave 0..15
  const int ln = t & 63;
  const float* Xb = g_X + (size_t)b*NN;
  const float* Yb = g_Y + (size_t)b*NN;
  const float* Zb = g_Z + (size_t)b*NN;

  __shared__ unsigned sE[256];               // 16 waves x 16 smallest e1-keys
  __shared__ unsigned long long s_cand[512]; // candidate (key,idx)
  __shared__ int s_cnt;

  const float* cp = g_center + (size_t)bg*3;
  float cx = cp[0], cy = cp[1], cz = cp[2];
  float cn2 = rn_add(rn_add(rn_mul(cx,cx), rn_mul(cy,cy)), rn_mul(cz,cz));

  // ---- 1: d2 of 32 points/lane (identical formula as validated) + top-2 ----
  float d2r[32];
  float e0 = INFINITY, e1 = INFINITY;
  #pragma unroll
  for (int s = 0; s < 32; ++s){
    int i = (w << 11) + (s << 6) + ln;
    float x = Xb[i], y = Yb[i], z = Zb[i];
    float n2 = rn_add(rn_add(rn_mul(x,x), rn_mul(y,y)), rn_mul(z,z));
    float e  = rn_add(rn_add(rn_mul(cx,x), rn_mul(cy,y)), rn_mul(cz,z));
    float d  = rn_sub(rn_add(cn2, n2), rn_add(e,e));
    d2r[s] = d;
    if (d < e1){ if (d < e0){ e1 = e0; e0 = d; } else e1 = d; }
  }

  // ---- 2: per-wave bitonic sort of e1 keys (ascending across lanes) ----
  {
    unsigned v = fkey(e1);
    #pragma unroll
    for (int k = 2; k <= 64; k <<= 1){
      #pragma unroll
      for (int j = k >> 1; j > 0; j >>= 1){
        unsigned o = (unsigned)__shfl_xor((int)v, j);
        bool keepmin = (((ln & k) == 0) == ((ln & j) == 0));
        unsigned mn = o < v ? o : v;
        unsigned mx = o < v ? v : o;
        v = keepmin ? mn : mx;
      }
    }
    if (ln < 16) sE[w*16 + ln] = v;
  }
  if (t == 0) s_cnt = 0;
  __syncthreads();

  // ---- 3: T = 16th smallest of sE[256] (all waves, redundant/uniform) ----
  unsigned T;
  {
    unsigned a0 = sE[ln*4+0], a1 = sE[ln*4+1], a2 = sE[ln*4+2], a3 = sE[ln*4+3];
    for (int r = 0; r < 16; ++r){
      unsigned m = a0 < a1 ? a0 : a1;
      unsigned m2 = a2 < a3 ? a2 : a3;
      m = m < m2 ? m : m2;
      #pragma unroll
      for (int off = 32; off >= 1; off >>= 1){
        unsigned o = (unsigned)__shfl_xor((int)m, off);
        m = o < m ? o : m;
      }
      T = m;
      unsigned long long msk = __ballot(a0 == m || a1 == m || a2 == m || a3 == m);
      int fl = __ffsll((long long)msk) - 1;
      if (ln == fl){
        if (a0 == m) a0 = 0xFFFFFFFFu;
        else if (a1 == m) a1 = 0xFFFFFFFFu;
        else if (a2 == m) a2 = 0xFFFFFFFFu;
        else a3 = 0xFFFFFFFFu;
      }
    }
  }

  // ---- 4: collect candidates key(d2) <= T ----
  #pragma unroll
  for (int s = 0; s < 32; ++s){
    if (fkey(d2r[s]) <= T){
      int i = (w << 11) + (s << 6) + ln;
      int p = atomicAdd(&s_cnt, 1);
      if (p < 512)
        s_cand[p] = ((unsigned long long)fkey(d2r[s]) << 32) | (unsigned)i;
    }
  }
  __syncthreads();

  // ---- 5: wave 0 selects exact top-32 by (d2, idx) ----
  if (w == 0){
    int C = s_cnt; if (C > 512) C = 512;
    int* kout = g_knn + (size_t)bg*KK;
    if (C <= 64){
      unsigned long long kk = (ln < C) ? s_cand[ln] : ~0ull;
      #pragma unroll
      for (int k = 2; k <= 64; k <<= 1){
        #pragma unroll
        for (int j = k >> 1; j > 0; j >>= 1){
          unsigned long long o = (unsigned long long)__shfl_xor((long long)kk, j);
          bool keepmin = (((ln & k) == 0) == ((ln & j) == 0));
          unsigned long long mn = o < kk ? o : kk;
          unsigned long long mx = o < kk ? kk : o;
          kk = keepmin ? mn : mx;
        }
      }
      if (ln < KK) kout[ln] = (int)(kk & 0xffffffffu);
    } else {
      unsigned long long md[8];
      #pragma unroll
      for (int j = 0; j < 8; ++j){
        int e = ln + (j << 6);
        md[j] = (e < C) ? s_cand[e] : ~0ull;
      }
      for (int r = 0; r < KK; ++r){
        unsigned long long bk = md[0];
        #pragma unroll
        for (int j = 1; j < 8; ++j) if (md[j] < bk) bk = md[j];
        #pragma unroll
        for (int off = 32; off >= 1; off >>= 1){
          unsigned long long o = (unsigned long long)__shfl_xor((long long)bk, off);
          if (o < bk) bk = o;
        }
        #pragma unroll
        for (int j = 0; j < 8; ++j) if (md[j] == bk) md[j] = ~0ull;  // keys unique
        if (ln == 0) kout[r] = (int)(bk & 0xffffffffu);
      }
    }
  }
}

// ---------------------------------------------------------------------------
// MLP 6->64->128->384 + maxpool over K. 1 block per (b,g), 256 threads.
// ---------------------------------------------------------------------------
__global__ __launch_bounds__(256) void k_mlp(const float* __restrict__ xyz,
                                             const float* __restrict__ feat,
                                             float* __restrict__ outPatch){
  const int bg = blockIdx.x;
  const int b  = bg >> 6;
  const int t  = threadIdx.x;
  const float* xb = xyz  + (size_t)b*NN*3;
  const float* fb = feat + (size_t)b*NN*3;

  __shared__ float h0[KK][8];
  __shared__ float h1[KK][68];
  __shared__ float h2[KK][132];
  __shared__ float pmax[4][DD];

  if (t < KK){
    int idx = g_knn[(size_t)bg*KK + t] & (NN - 1);   // defensive clamp (power of 2)
    const float* cp = g_center + (size_t)bg*3;
    h0[t][0] = rn_sub(xb[idx*3+0], cp[0]);
    h0[t][1] = rn_sub(xb[idx*3+1], cp[1]);
    h0[t][2] = rn_sub(xb[idx*3+2], cp[2]);
    h0[t][3] = fb[idx*3+0];
    h0[t][4] = fb[idx*3+1];
    h0[t][5] = fb[idx*3+2];
  }
  __syncthreads();

  { // L1: 32k x 64o, thread = (k, 8 o's)
    int k = t >> 3, ob = (t & 7) * 8;
    float acc[8];
    #pragma unroll
    for (int j = 0; j < 8; ++j) acc[j] = g_b1[ob + j];
    #pragma unroll
    for (int c = 0; c < 6; ++c){
      float a = h0[k][c];
      const float4* wr = (const float4*)(g_w1t + c*64 + ob);
      float4 wa = wr[0], wb = wr[1];
      acc[0] = fmaf(a, wa.x, acc[0]); acc[1] = fmaf(a, wa.y, acc[1]);
      acc[2] = fmaf(a, wa.z, acc[2]); acc[3] = fmaf(a, wa.w, acc[3]);
      acc[4] = fmaf(a, wb.x, acc[4]); acc[5] = fmaf(a, wb.y, acc[5]);
      acc[6] = fmaf(a, wb.z, acc[6]); acc[7] = fmaf(a, wb.w, acc[7]);
    }
    #pragma unroll
    for (int j = 0; j < 8; ++j) h1[k][ob + j] = fmaxf(acc[j], 0.f);
  }
  __syncthreads();

  { // L2: 32k x 128o, thread = (k, 16 o's)
    int k = t >> 3, ob = (t & 7) * 16;
    float acc[16];
    #pragma unroll
    for (int j = 0; j < 16; ++j) acc[j] = g_b2[ob + j];
    for (int c = 0; c < 64; ++c){
      float a = h1[k][c];
      const float4* wr = (const float4*)(g_w2t + c*128 + ob);
      #pragma unroll
      for (int q = 0; q < 4; ++q){
        float4 w4 = wr[q];
        acc[q*4+0] = fmaf(a, w4.x, acc[q*4+0]);
        acc[q*4+1] = fmaf(a, w4.y, acc[q*4+1]);
        acc[q*4+2] = fmaf(a, w4.z, acc[q*4+2]);
        acc[q*4+3] = fmaf(a, w4.w, acc[q*4+3]);
      }
    }
    #pragma unroll
    for (int j = 0; j < 16; ++j) h2[k][ob + j] = fmaxf(acc[j], 0.f);
  }
  __syncthreads();

  { // L3: 32k x 384o + partial max over k. wave wv owns k in [8wv,8wv+8).
    int wv = t >> 6, ln = t & 63;
    float acc[8][6];
    #pragma unroll
    for (int kk = 0; kk < 8; ++kk)
      #pragma unroll
      for (int j = 0; j < 6; ++j) acc[kk][j] = 0.f;
    for (int c = 0; c < 128; ++c){
      float hk[8];
      #pragma unroll
      for (int kk = 0; kk < 8; ++kk) hk[kk] = h2[wv*8 + kk][c];  // broadcast
      float wj[6];
      #pragma unroll
      for (int j = 0; j < 6; ++j) wj[j] = g_w3t[c*384 + ln + 64*j]; // coalesced
      #pragma unroll
      for (int kk = 0; kk < 8; ++kk)
        #pragma unroll
        for (int j = 0; j < 6; ++j) acc[kk][j] = fmaf(hk[kk], wj[j], acc[kk][j]);
    }
    #pragma unroll
    for (int j = 0; j < 6; ++j){
      float m = acc[0][j];
      #pragma unroll
      for (int kk = 1; kk < 8; ++kk) m = fmaxf(m, acc[kk][j]);
      pmax[wv][ln + 64*j] = m;
    }
  }
  __syncthreads();

  if (t < 128){
    #pragma unroll
    for (int s = 0; s < 3; ++s){
      int o = t + 128*s;
      float m = fmaxf(fmaxf(pmax[0][o], pmax[1][o]), fmaxf(pmax[2][o], pmax[3][o]));
      outPatch[(size_t)bg*DD + o] = m + g_b3[o];
    }
  }
}

// ---------------------------------------------------------------------------
extern "C" void kernel_launch(void* const* d_in, const int* in_sizes, int n_in,
                              void* d_out, int out_size, void* d_ws, size_t ws_size,
                              hipStream_t stream){
  (void)in_sizes; (void)n_in; (void)out_size; (void)d_ws; (void)ws_size;
  const float* xyz  = (const float*)d_in[0];
  const float* feat = (const float*)d_in[1];
  const float* w1 = (const float*)d_in[2];
  const float* g1 = (const float*)d_in[3];
  const float* b1 = (const float*)d_in[4];
  const float* m1 = (const float*)d_in[5];
  const float* v1 = (const float*)d_in[6];
  const float* w2 = (const float*)d_in[7];
  const float* g2 = (const float*)d_in[8];
  const float* b2 = (const float*)d_in[9];
  const float* m2 = (const float*)d_in[10];
  const float* v2 = (const float*)d_in[11];
  const float* w3 = (const float*)d_in[12];
  const float* g3 = (const float*)d_in[13];
  const float* b3 = (const float*)d_in[14];
  const float* m3 = (const float*)d_in[15];
  const float* v3 = (const float*)d_in[16];
  float* out = (float*)d_out;

  k_prep<<<64, 256, 0, stream>>>(w1,g1,b1,m1,v1, w2,g2,b2,m2,v2, w3,g3,b3,m3,v3);
  k_soa<<<(BB*NN)/256, 256, 0, stream>>>(xyz);
  k_fps<<<BB, 1024, 0, stream>>>(xyz, out);
  k_knn<<<BB*GG, 1024, 0, stream>>>();
  k_mlp<<<BB*GG, 256, 0, stream>>>(xyz, feat, out + (size_t)BB*GG*3);
}

// Round 9
// 864.809 us; speedup vs baseline: 1.6229x; 1.6229x over previous
//
#include <hip/hip_runtime.h>
#include <hip/hip_bf16.h>

#define BB 32
#define NN 32768
#define GG 64
#define KK 32
#define DD 384
#define EPSF 1e-5f
#define FPS_NBLK 8          // blocks per batch for k_fps
#define FPS_PTS  16         // points per thread (4096 per block / 256 thr)

__device__ __forceinline__ float rn_add(float a, float b){ return __fadd_rn(a,b); }
__device__ __forceinline__ float rn_sub(float a, float b){ return __fsub_rn(a,b); }
__device__ __forceinline__ float rn_mul(float a, float b){ return __fmul_rn(a,b); }

// monotone float->u32 map: preserves total order of finite floats
__device__ __forceinline__ unsigned fkey(float d){
  unsigned u = __float_as_uint(d);
  return (u & 0x80000000u) ? ~u : (u | 0x80000000u);
}

#define REP16(X) X(0) X(1) X(2) X(3) X(4) X(5) X(6) X(7) \
                 X(8) X(9) X(10) X(11) X(12) X(13) X(14) X(15)

// ---- module-scope scratch: avoids any assumption about ws_size ------------
__device__ float g_center[BB*GG*3];     // 24 KB
__device__ int   g_knn[BB*GG*KK];       // 256 KB
__device__ float g_w1t[6*64];           // folded, transposed weights
__device__ float g_b1[64];
__device__ float g_w2t[64*128];
__device__ float g_b2[128];
__device__ float g_w3t[128*384];
__device__ float g_b3[384];
__device__ float g_X[BB*NN];            // 4 MB SoA coords (bit-exact copies)
__device__ float g_Y[BB*NN];            // 4 MB
__device__ float g_Z[BB*NN];            // 4 MB
__device__ unsigned long long g_fkey[BB*GG];  // per-(batch,iter) argmax key
__device__ unsigned           g_fcnt[BB*GG];  // per-(batch,iter) arrival count

// ---------------------------------------------------------------------------
// One-shot AoS -> SoA repack (bit-exact copy).
// ---------------------------------------------------------------------------
__global__ __launch_bounds__(256) void k_soa(const float* __restrict__ xyz){
  int tid = blockIdx.x * blockDim.x + threadIdx.x;   // 0 .. BB*NN-1
  int b = tid >> 15;                                  // NN = 2^15
  int p = tid & (NN - 1);
  const float* s = xyz + (size_t)b*NN*3 + (size_t)p*3;
  g_X[tid] = s[0];
  g_Y[tid] = s[1];
  g_Z[tid] = s[2];
}

// zero the fps sync slots (every call: graph replays must be deterministic)
__global__ __launch_bounds__(256) void k_zero(void){
  int tid = blockIdx.x * blockDim.x + threadIdx.x;
  if (tid < BB*GG){ g_fkey[tid] = 0ull; g_fcnt[tid] = 0u; }
}

// ---------------------------------------------------------------------------
// Weight prep: fold BN (scale,shift) into transposed weights.
// ---------------------------------------------------------------------------
__global__ void k_prep(const float* __restrict__ w1, const float* __restrict__ g1, const float* __restrict__ b1, const float* __restrict__ m1, const float* __restrict__ v1,
                       const float* __restrict__ w2, const float* __restrict__ g2, const float* __restrict__ b2, const float* __restrict__ m2, const float* __restrict__ v2,
                       const float* __restrict__ w3, const float* __restrict__ g3, const float* __restrict__ b3, const float* __restrict__ m3, const float* __restrict__ v3){
  int tid = blockIdx.x * blockDim.x + threadIdx.x;
  int nt  = gridDim.x * blockDim.x;
  for (int e = tid; e < 64*6; e += nt){
    int c = e >> 6, o = e & 63;
    float s = g1[o] * rsqrtf(v1[o] + EPSF);
    g_w1t[e] = w1[o*6 + c] * s;
  }
  for (int o = tid; o < 64; o += nt){
    float s = g1[o] * rsqrtf(v1[o] + EPSF);
    g_b1[o] = b1[o] - m1[o]*s;
  }
  for (int e = tid; e < 64*128; e += nt){
    int c = e >> 7, o = e & 127;
    float s = g2[o] * rsqrtf(v2[o] + EPSF);
    g_w2t[e] = w2[o*64 + c] * s;
  }
  for (int o = tid; o < 128; o += nt){
    float s = g2[o] * rsqrtf(v2[o] + EPSF);
    g_b2[o] = b2[o] - m2[o]*s;
  }
  for (int e = tid; e < 384*128; e += nt){   // e = o*128+c (input-major)
    int o = e >> 7, c = e & 127;
    float s = g3[o] * rsqrtf(v3[o] + EPSF);
    g_w3t[c*384 + o] = w3[e] * s;
  }
  for (int o = tid; o < 384; o += nt){
    float s = g3[o] * rsqrtf(v3[o] + EPSF);
    g_b3[o] = b3[o] - m3[o]*s;
  }
}

// ---------------------------------------------------------------------------
// FPS v4: 8 blocks/batch x 256 threads, 16 pts/thread.
// r5-r8 lesson: 1024-thread kernels get a hard 64-VGPR allocation (three
// independent knobs no-op'd) -> any state >~40 floats spills to scratch.
// Here per-thread state = dd0..dd15 (+temps) ~= 40 VGPR: provably fits.
// Coords re-read per iter from SoA (block slice = 48 KB, L2-resident).
// Cross-block argmax: composite u64 key (fkey(d)<<32)|(~idx) -> atomicMax
// per (batch,iter) slot + arrival counter + spin (device-scope atomics,
// m20). Grid=256=#CUs, 4 waves, <=64 VGPR -> all blocks resident, no
// deadlock. Selection semantics EXACTLY numpy argmax (max d, min idx).
// ---------------------------------------------------------------------------
__global__ __launch_bounds__(256)
void k_fps(float* __restrict__ outCenter){
  const int blk = blockIdx.x;
  const int b   = blk >> 3;          // batch
  const int sub = blk & 7;           // sub-block within batch
  const int t   = threadIdx.x;
  const int wv  = t >> 6, ln = t & 63;
  const int base = sub * (NN / FPS_NBLK);   // 4096-point slice
  const float* Xb = g_X + (size_t)b*NN;
  const float* Yb = g_Y + (size_t)b*NN;
  const float* Zb = g_Z + (size_t)b*NN;

  __shared__ unsigned long long skey[4];
  __shared__ int swin;

#define DD_DECL(i) float dd##i = 1e10f;
  REP16(DD_DECL)
#undef DD_DECL

  int far = 0;
  for (int it = 0; ; ++it){
    if (sub == 0 && t == 0){
      float cx = Xb[far], cy = Yb[far], cz = Zb[far];
      float* cw = g_center  + (size_t)(b*GG + it)*3;
      float* co = outCenter + (size_t)(b*GG + it)*3;
      cw[0] = cx; cw[1] = cy; cw[2] = cz;
      co[0] = cx; co[1] = cy; co[2] = cz;
    }
    if (it == GG - 1) break;

    float cx = Xb[far], cy = Yb[far], cz = Zb[far];   // broadcast loads
    unsigned long long bk = 0ull;
    // i ascending => point idx ascending; keys unique (idx embedded) so the
    // max-key is exactly (max d, tie -> lowest idx) == numpy argmax.
#define DD_UPD(i) { \
    int p = base + (i << 8) + t; \
    float dx = rn_sub(Xb[p], cx); \
    float dy = rn_sub(Yb[p], cy); \
    float dz = rn_sub(Zb[p], cz); \
    float s_ = rn_add(rn_add(rn_mul(dx,dx), rn_mul(dy,dy)), rn_mul(dz,dz)); \
    float d_ = fminf(dd##i, s_); \
    dd##i = d_; \
    unsigned long long k_ = ((unsigned long long)fkey(d_) << 32) \
                          | (unsigned)(0xFFFFFFFFu - (unsigned)p); \
    if (k_ > bk) bk = k_; }
    REP16(DD_UPD)
#undef DD_UPD

    #pragma unroll
    for (int off = 32; off >= 1; off >>= 1){
      unsigned long long o = (unsigned long long)__shfl_xor((long long)bk, off);
      if (o > bk) bk = o;
    }
    if (ln == 0) skey[wv] = bk;
    __syncthreads();
    if (t == 0){
      unsigned long long m = skey[0];
      if (skey[1] > m) m = skey[1];
      if (skey[2] > m) m = skey[2];
      if (skey[3] > m) m = skey[3];
      int slot = (b << 6) + it;
      atomicMax(&g_fkey[slot], m);
      __threadfence();
      atomicAdd(&g_fcnt[slot], 1u);
      while (atomicAdd(&g_fcnt[slot], 0u) < FPS_NBLK) { }
      unsigned long long w = atomicMax(&g_fkey[slot], 0ull);
      swin = (int)(0xFFFFFFFFu - (unsigned)(w & 0xFFFFFFFFu));
    }
    __syncthreads();
    far = swin;
  }
}

// ---------------------------------------------------------------------------
// KNN v3, exact, threshold-based (validated r5/r8); SoA coalesced loads.
// ---------------------------------------------------------------------------
__global__ __launch_bounds__(1024) void k_knn(void){
  const int bg = blockIdx.x;        // b*64+g
  const int b  = bg >> 6;
  const int t  = threadIdx.x;       // 0..1023
  const int w  = t >> 6;            // wave 0..15
  const int ln = t & 63;
  const float* Xb = g_X + (size_t)b*NN;
  const float* Yb = g_Y + (size_t)b*NN;
  const float* Zb = g_Z + (size_t)b*NN;

  __shared__ unsigned sE[256];               // 16 waves x 16 smallest e1-keys
  __shared__ unsigned long long s_cand[512]; // candidate (key,idx)
  __shared__ int s_cnt;

  const float* cp = g_center + (size_t)bg*3;
  float cx = cp[0], cy = cp[1], cz = cp[2];
  float cn2 = rn_add(rn_add(rn_mul(cx,cx), rn_mul(cy,cy)), rn_mul(cz,cz));

  // ---- 1: d2 of 32 points/lane (identical formula as validated) + top-2 ----
  float d2r[32];
  float e0 = INFINITY, e1 = INFINITY;
  #pragma unroll
  for (int s = 0; s < 32; ++s){
    int i = (w << 11) + (s << 6) + ln;
    float x = Xb[i], y = Yb[i], z = Zb[i];
    float n2 = rn_add(rn_add(rn_mul(x,x), rn_mul(y,y)), rn_mul(z,z));
    float e  = rn_add(rn_add(rn_mul(cx,x), rn_mul(cy,y)), rn_mul(cz,z));
    float d  = rn_sub(rn_add(cn2, n2), rn_add(e,e));
    d2r[s] = d;
    if (d < e1){ if (d < e0){ e1 = e0; e0 = d; } else e1 = d; }
  }

  // ---- 2: per-wave bitonic sort of e1 keys (ascending across lanes) ----
  {
    unsigned v = fkey(e1);
    #pragma unroll
    for (int k = 2; k <= 64; k <<= 1){
      #pragma unroll
      for (int j = k >> 1; j > 0; j >>= 1){
        unsigned o = (unsigned)__shfl_xor((int)v, j);
        bool keepmin = (((ln & k) == 0) == ((ln & j) == 0));
        unsigned mn = o < v ? o : v;
        unsigned mx = o < v ? v : o;
        v = keepmin ? mn : mx;
      }
    }
    if (ln < 16) sE[w*16 + ln] = v;
  }
  if (t == 0) s_cnt = 0;
  __syncthreads();

  // ---- 3: T = 16th smallest of sE[256] (all waves, redundant/uniform) ----
  unsigned T;
  {
    unsigned a0 = sE[ln*4+0], a1 = sE[ln*4+1], a2 = sE[ln*4+2], a3 = sE[ln*4+3];
    for (int r = 0; r < 16; ++r){
      unsigned m = a0 < a1 ? a0 : a1;
      unsigned m2 = a2 < a3 ? a2 : a3;
      m = m < m2 ? m : m2;
      #pragma unroll
      for (int off = 32; off >= 1; off >>= 1){
        unsigned o = (unsigned)__shfl_xor((int)m, off);
        m = o < m ? o : m;
      }
      T = m;
      unsigned long long msk = __ballot(a0 == m || a1 == m || a2 == m || a3 == m);
      int fl = __ffsll((long long)msk) - 1;
      if (ln == fl){
        if (a0 == m) a0 = 0xFFFFFFFFu;
        else if (a1 == m) a1 = 0xFFFFFFFFu;
        else if (a2 == m) a2 = 0xFFFFFFFFu;
        else a3 = 0xFFFFFFFFu;
      }
    }
  }

  // ---- 4: collect candidates key(d2) <= T ----
  #pragma unroll
  for (int s = 0; s < 32; ++s){
    if (fkey(d2r[s]) <= T){
      int i = (w << 11) + (s << 6) + ln;
      int p = atomicAdd(&s_cnt, 1);
      if (p < 512)
        s_cand[p] = ((unsigned long long)fkey(d2r[s]) << 32) | (unsigned)i;
    }
  }
  __syncthreads();

  // ---- 5: wave 0 selects exact top-32 by (d2, idx) ----
  if (w == 0){
    int C = s_cnt; if (C > 512) C = 512;
    int* kout = g_knn + (size_t)bg*KK;
    if (C <= 64){
      unsigned long long kk = (ln < C) ? s_cand[ln] : ~0ull;
      #pragma unroll
      for (int k = 2; k <= 64; k <<= 1){
        #pragma unroll
        for (int j = k >> 1; j > 0; j >>= 1){
          unsigned long long o = (unsigned long long)__shfl_xor((long long)kk, j);
          bool keepmin = (((ln & k) == 0) == ((ln & j) == 0));
          unsigned long long mn = o < kk ? o : kk;
          unsigned long long mx = o < kk ? kk : o;
          kk = keepmin ? mn : mx;
        }
      }
      if (ln < KK) kout[ln] = (int)(kk & 0xffffffffu);
    } else {
      unsigned long long md[8];
      #pragma unroll
      for (int j = 0; j < 8; ++j){
        int e = ln + (j << 6);
        md[j] = (e < C) ? s_cand[e] : ~0ull;
      }
      for (int r = 0; r < KK; ++r){
        unsigned long long bk = md[0];
        #pragma unroll
        for (int j = 1; j < 8; ++j) if (md[j] < bk) bk = md[j];
        #pragma unroll
        for (int off = 32; off >= 1; off >>= 1){
          unsigned long long o = (unsigned long long)__shfl_xor((long long)bk, off);
          if (o < bk) bk = o;
        }
        #pragma unroll
        for (int j = 0; j < 8; ++j) if (md[j] == bk) md[j] = ~0ull;  // keys unique
        if (ln == 0) kout[r] = (int)(bk & 0xffffffffu);
      }
    }
  }
}

// ---------------------------------------------------------------------------
// MLP 6->64->128->384 + maxpool over K. 1 block per (b,g), 256 threads.
// ---------------------------------------------------------------------------
__global__ __launch_bounds__(256) void k_mlp(const float* __restrict__ xyz,
                                             const float* __restrict__ feat,
                                             float* __restrict__ outPatch){
  const int bg = blockIdx.x;
  const int b  = bg >> 6;
  const int t  = threadIdx.x;
  const float* xb = xyz  + (size_t)b*NN*3;
  const float* fb = feat + (size_t)b*NN*3;

  __shared__ float h0[KK][8];
  __shared__ float h1[KK][68];
  __shared__ float h2[KK][132];
  __shared__ float pmax[4][DD];

  if (t < KK){
    int idx = g_knn[(size_t)bg*KK + t] & (NN - 1);   // defensive clamp (power of 2)
    const float* cp = g_center + (size_t)bg*3;
    h0[t][0] = rn_sub(xb[idx*3+0], cp[0]);
    h0[t][1] = rn_sub(xb[idx*3+1], cp[1]);
    h0[t][2] = rn_sub(xb[idx*3+2], cp[2]);
    h0[t][3] = fb[idx*3+0];
    h0[t][4] = fb[idx*3+1];
    h0[t][5] = fb[idx*3+2];
  }
  __syncthreads();

  { // L1: 32k x 64o, thread = (k, 8 o's)
    int k = t >> 3, ob = (t & 7) * 8;
    float acc[8];
    #pragma unroll
    for (int j = 0; j < 8; ++j) acc[j] = g_b1[ob + j];
    #pragma unroll
    for (int c = 0; c < 6; ++c){
      float a = h0[k][c];
      const float4* wr = (const float4*)(g_w1t + c*64 + ob);
      float4 wa = wr[0], wb = wr[1];
      acc[0] = fmaf(a, wa.x, acc[0]); acc[1] = fmaf(a, wa.y, acc[1]);
      acc[2] = fmaf(a, wa.z, acc[2]); acc[3] = fmaf(a, wa.w, acc[3]);
      acc[4] = fmaf(a, wb.x, acc[4]); acc[5] = fmaf(a, wb.y, acc[5]);
      acc[6] = fmaf(a, wb.z, acc[6]); acc[7] = fmaf(a, wb.w, acc[7]);
    }
    #pragma unroll
    for (int j = 0; j < 8; ++j) h1[k][ob + j] = fmaxf(acc[j], 0.f);
  }
  __syncthreads();

  { // L2: 32k x 128o, thread = (k, 16 o's)
    int k = t >> 3, ob = (t & 7) * 16;
    float acc[16];
    #pragma unroll
    for (int j = 0; j < 16; ++j) acc[j] = g_b2[ob + j];
    for (int c = 0; c < 64; ++c){
      float a = h1[k][c];
      const float4* wr = (const float4*)(g_w2t + c*128 + ob);
      #pragma unroll
      for (int q = 0; q < 4; ++q){
        float4 w4 = wr[q];
        acc[q*4+0] = fmaf(a, w4.x, acc[q*4+0]);
        acc[q*4+1] = fmaf(a, w4.y, acc[q*4+1]);
        acc[q*4+2] = fmaf(a, w4.z, acc[q*4+2]);
        acc[q*4+3] = fmaf(a, w4.w, acc[q*4+3]);
      }
    }
    #pragma unroll
    for (int j = 0; j < 16; ++j) h2[k][ob + j] = fmaxf(acc[j], 0.f);
  }
  __syncthreads();

  { // L3: 32k x 384o + partial max over k. wave wv owns k in [8wv,8wv+8).
    int wv = t >> 6, ln = t & 63;
    float acc[8][6];
    #pragma unroll
    for (int kk = 0; kk < 8; ++kk)
      #pragma unroll
      for (int j = 0; j < 6; ++j) acc[kk][j] = 0.f;
    for (int c = 0; c < 128; ++c){
      float hk[8];
      #pragma unroll
      for (int kk = 0; kk < 8; ++kk) hk[kk] = h2[wv*8 + kk][c];  // broadcast
      float wj[6];
      #pragma unroll
      for (int j = 0; j < 6; ++j) wj[j] = g_w3t[c*384 + ln + 64*j]; // coalesced
      #pragma unroll
      for (int kk = 0; kk < 8; ++kk)
        #pragma unroll
        for (int j = 0; j < 6; ++j) acc[kk][j] = fmaf(hk[kk], wj[j], acc[kk][j]);
    }
    #pragma unroll
    for (int j = 0; j < 6; ++j){
      float m = acc[0][j];
      #pragma unroll
      for (int kk = 1; kk < 8; ++kk) m = fmaxf(m, acc[kk][j]);
      pmax[wv][ln + 64*j] = m;
    }
  }
  __syncthreads();

  if (t < 128){
    #pragma unroll
    for (int s = 0; s < 3; ++s){
      int o = t + 128*s;
      float m = fmaxf(fmaxf(pmax[0][o], pmax[1][o]), fmaxf(pmax[2][o], pmax[3][o]));
      outPatch[(size_t)bg*DD + o] = m + g_b3[o];
    }
  }
}

// ---------------------------------------------------------------------------
extern "C" void kernel_launch(void* const* d_in, const int* in_sizes, int n_in,
                              void* d_out, int out_size, void* d_ws, size_t ws_size,
                              hipStream_t stream){
  (void)in_sizes; (void)n_in; (void)out_size; (void)d_ws; (void)ws_size;
  const float* xyz  = (const float*)d_in[0];
  const float* feat = (const float*)d_in[1];
  const float* w1 = (const float*)d_in[2];
  const float* g1 = (const float*)d_in[3];
  const float* b1 = (const float*)d_in[4];
  const float* m1 = (const float*)d_in[5];
  const float* v1 = (const float*)d_in[6];
  const float* w2 = (const float*)d_in[7];
  const float* g2 = (const float*)d_in[8];
  const float* b2 = (const float*)d_in[9];
  const float* m2 = (const float*)d_in[10];
  const float* v2 = (const float*)d_in[11];
  const float* w3 = (const float*)d_in[12];
  const float* g3 = (const float*)d_in[13];
  const float* b3 = (const float*)d_in[14];
  const float* m3 = (const float*)d_in[15];
  const float* v3 = (const float*)d_in[16];
  float* out = (float*)d_out;

  k_prep<<<64, 256, 0, stream>>>(w1,g1,b1,m1,v1, w2,g2,b2,m2,v2, w3,g3,b3,m3,v3);
  k_soa<<<(BB*NN)/256, 256, 0, stream>>>(xyz);
  k_zero<<<8, 256, 0, stream>>>();
  k_fps<<<BB*FPS_NBLK, 256, 0, stream>>>(out);
  k_knn<<<BB*GG, 1024, 0, stream>>>();
  k_mlp<<<BB*GG, 256, 0, stream>>>(xyz, feat, out + (size_t)BB*GG*3);
}

// Round 10
// 576.962 us; speedup vs baseline: 2.4326x; 1.4989x over previous
//
#include <hip/hip_runtime.h>
#include <hip/hip_bf16.h>

#define BB 32
#define NN 32768
#define GG 64
#define KK 32
#define DD 384
#define EPSF 1e-5f
#define FPS_NBLK 8          // blocks per batch for k_fps
#define FPS_SL   (NN/FPS_NBLK)   // 4096-point slice per block

__device__ __forceinline__ float rn_add(float a, float b){ return __fadd_rn(a,b); }
__device__ __forceinline__ float rn_sub(float a, float b){ return __fsub_rn(a,b); }
__device__ __forceinline__ float rn_mul(float a, float b){ return __fmul_rn(a,b); }

// monotone float->u32 map: preserves total order of finite floats.
// For d >= 0 (our case): result >= 0x80000000 -> composite key never 0.
__device__ __forceinline__ unsigned fkey(float d){
  unsigned u = __float_as_uint(d);
  return (u & 0x80000000u) ? ~u : (u | 0x80000000u);
}

#define REP16(X) X(0) X(1) X(2) X(3) X(4) X(5) X(6) X(7) \
                 X(8) X(9) X(10) X(11) X(12) X(13) X(14) X(15)

// ---- module-scope scratch: avoids any assumption about ws_size ------------
__device__ float g_center[BB*GG*3];     // 24 KB
__device__ int   g_knn[BB*GG*KK];       // 256 KB
__device__ float g_w1t[6*64];           // folded, transposed weights
__device__ float g_b1[64];
__device__ float g_w2t[64*128];
__device__ float g_b2[128];
__device__ float g_w3t[128*384];
__device__ float g_b3[384];
__device__ float g_X[BB*NN];            // 4 MB SoA coords (bit-exact copies)
__device__ float g_Y[BB*NN];            // 4 MB
__device__ float g_Z[BB*NN];            // 4 MB
__device__ unsigned long long g_part[BB*FPS_NBLK*GG];  // per-(b,sub,iter) keys, 128 KB

// ---------------------------------------------------------------------------
// One-shot AoS -> SoA repack (bit-exact copy).
// ---------------------------------------------------------------------------
__global__ __launch_bounds__(256) void k_soa(const float* __restrict__ xyz){
  int tid = blockIdx.x * blockDim.x + threadIdx.x;   // 0 .. BB*NN-1
  int b = tid >> 15;                                  // NN = 2^15
  int p = tid & (NN - 1);
  const float* s = xyz + (size_t)b*NN*3 + (size_t)p*3;
  g_X[tid] = s[0];
  g_Y[tid] = s[1];
  g_Z[tid] = s[2];
}

// zero the fps slots (every call: graph replays must be deterministic)
__global__ __launch_bounds__(256) void k_zero(void){
  int tid = blockIdx.x * blockDim.x + threadIdx.x;
  if (tid < BB*FPS_NBLK*GG) g_part[tid] = 0ull;
}

// ---------------------------------------------------------------------------
// Weight prep: fold BN (scale,shift) into transposed weights.
// ---------------------------------------------------------------------------
__global__ void k_prep(const float* __restrict__ w1, const float* __restrict__ g1, const float* __restrict__ b1, const float* __restrict__ m1, const float* __restrict__ v1,
                       const float* __restrict__ w2, const float* __restrict__ g2, const float* __restrict__ b2, const float* __restrict__ m2, const float* __restrict__ v2,
                       const float* __restrict__ w3, const float* __restrict__ g3, const float* __restrict__ b3, const float* __restrict__ m3, const float* __restrict__ v3){
  int tid = blockIdx.x * blockDim.x + threadIdx.x;
  int nt  = gridDim.x * blockDim.x;
  for (int e = tid; e < 64*6; e += nt){
    int c = e >> 6, o = e & 63;
    float s = g1[o] * rsqrtf(v1[o] + EPSF);
    g_w1t[e] = w1[o*6 + c] * s;
  }
  for (int o = tid; o < 64; o += nt){
    float s = g1[o] * rsqrtf(v1[o] + EPSF);
    g_b1[o] = b1[o] - m1[o]*s;
  }
  for (int e = tid; e < 64*128; e += nt){
    int c = e >> 7, o = e & 127;
    float s = g2[o] * rsqrtf(v2[o] + EPSF);
    g_w2t[e] = w2[o*64 + c] * s;
  }
  for (int o = tid; o < 128; o += nt){
    float s = g2[o] * rsqrtf(v2[o] + EPSF);
    g_b2[o] = b2[o] - m2[o]*s;
  }
  for (int e = tid; e < 384*128; e += nt){   // e = o*128+c (input-major)
    int o = e >> 7, c = e & 127;
    float s = g3[o] * rsqrtf(v3[o] + EPSF);
    g_w3t[c*384 + o] = w3[e] * s;
  }
  for (int o = tid; o < 384; o += nt){
    float s = g3[o] * rsqrtf(v3[o] + EPSF);
    g_b3[o] = b3[o] - m3[o]*s;
  }
}

// ---------------------------------------------------------------------------
// FPS v5: 8 blocks/batch x 256 threads, 16 pts/thread.
// r9 post-mortem: sync chain (serialized atomicMax/fence/add/spin by t==0,
// ~5 hops x ~1us cross-XCD) dominated at 7.2us/iter. Changes:
//  (a) slice coords staged in LDS (48KB) once -> inner loop reads LDS
//      (stride-1, conflict-free), no global loads per iter.
//  (b) sync = ONE atomicExch publish (key never 0: fkey>=0x80000000) +
//      lanes 0-7 poll the 8 slots IN PARALLEL + 3-step shuffle max.
// Selection semantics unchanged (validated r9): max composite key
// (fkey(d)<<32)|(~idx) == numpy argmax (max d, tie -> lowest idx).
// ---------------------------------------------------------------------------
__global__ __launch_bounds__(256)
void k_fps(float* __restrict__ outCenter){
  const int blk = blockIdx.x;
  const int b   = blk >> 3;          // batch
  const int sub = blk & 7;           // sub-block within batch
  const int t   = threadIdx.x;
  const int wv  = t >> 6, ln = t & 63;
  const int base = sub * FPS_SL;     // 4096-point slice
  const float* Xb = g_X + (size_t)b*NN;
  const float* Yb = g_Y + (size_t)b*NN;
  const float* Zb = g_Z + (size_t)b*NN;

  __shared__ float sx[FPS_SL], sy[FPS_SL], szz[FPS_SL];   // 48 KB
  __shared__ unsigned long long skey[4];
  __shared__ int s_far;

  #pragma unroll
  for (int i = 0; i < 16; ++i){
    int p = (i << 8) + t;
    sx[p]  = Xb[base + p];
    sy[p]  = Yb[base + p];
    szz[p] = Zb[base + p];
  }
  __syncthreads();

#define DD_DECL(i) float dd##i = 1e10f;
  REP16(DD_DECL)
#undef DD_DECL

  int far = 0;
  for (int it = 0; ; ++it){
    if (sub == 0 && t == 0){
      float cx = Xb[far], cy = Yb[far], cz = Zb[far];
      float* cw = g_center  + (size_t)(b*GG + it)*3;
      float* co = outCenter + (size_t)(b*GG + it)*3;
      cw[0] = cx; cw[1] = cy; cw[2] = cz;
      co[0] = cx; co[1] = cy; co[2] = cz;
    }
    if (it == GG - 1) break;

    float cx = Xb[far], cy = Yb[far], cz = Zb[far];   // broadcast loads (L2)
    unsigned long long bk = 0ull;
    // ascending i => ascending point idx; keys unique (idx embedded) so
    // max key == (max d, tie -> lowest idx) == numpy argmax.
#define DD_UPD(i) { \
    int p = (i << 8) + t; \
    float dx = rn_sub(sx[p], cx); \
    float dy = rn_sub(sy[p], cy); \
    float dz = rn_sub(szz[p], cz); \
    float s_ = rn_add(rn_add(rn_mul(dx,dx), rn_mul(dy,dy)), rn_mul(dz,dz)); \
    float d_ = fminf(dd##i, s_); \
    dd##i = d_; \
    unsigned long long k_ = ((unsigned long long)fkey(d_) << 32) \
                          | (unsigned)(0xFFFFFFFFu - (unsigned)(base + p)); \
    if (k_ > bk) bk = k_; }
    REP16(DD_UPD)
#undef DD_UPD

    #pragma unroll
    for (int off = 32; off >= 1; off >>= 1){
      unsigned long long o = (unsigned long long)__shfl_xor((long long)bk, off);
      if (o > bk) bk = o;
    }
    if (ln == 0) skey[wv] = bk;
    __syncthreads();
    if (wv == 0){
      // block max over the 4 wave keys (lanes 0-3), then publish
      unsigned long long m = (ln < 4) ? skey[ln] : 0ull;
      #pragma unroll
      for (int off = 1; off <= 2; off <<= 1){
        unsigned long long o = (unsigned long long)__shfl_xor((long long)m, off);
        if (o > m) m = o;
      }
      if (ln == 0)
        atomicExch(&g_part[(((b << 3) + sub) << 6) + it], m);
      // parallel poll: lane ln (0-7) waits for sub-block ln's key
      unsigned long long k = 0ull;
      if (ln < 8){
        unsigned long long* p = &g_part[(((b << 3) + ln) << 6) + it];
        do { k = atomicAdd(p, 0ull); } while (k == 0ull);
      }
      #pragma unroll
      for (int off = 1; off <= 4; off <<= 1){
        unsigned long long o = (unsigned long long)__shfl_xor((long long)k, off);
        if (o > k) k = o;
      }
      if (ln == 0) s_far = (int)(0xFFFFFFFFu - (unsigned)(k & 0xFFFFFFFFu));
    }
    __syncthreads();
    far = s_far;
  }
}

// ---------------------------------------------------------------------------
// KNN v3, exact, threshold-based (validated r5/r8); SoA coalesced loads.
// ---------------------------------------------------------------------------
__global__ __launch_bounds__(1024) void k_knn(void){
  const int bg = blockIdx.x;        // b*64+g
  const int b  = bg >> 6;
  const int t  = threadIdx.x;       // 0..1023
  const int w  = t >> 6;            // wave 0..15
  const int ln = t & 63;
  const float* Xb = g_X + (size_t)b*NN;
  const float* Yb = g_Y + (size_t)b*NN;
  const float* Zb = g_Z + (size_t)b*NN;

  __shared__ unsigned sE[256];               // 16 waves x 16 smallest e1-keys
  __shared__ unsigned long long s_cand[512]; // candidate (key,idx)
  __shared__ int s_cnt;

  const float* cp = g_center + (size_t)bg*3;
  float cx = cp[0], cy = cp[1], cz = cp[2];
  float cn2 = rn_add(rn_add(rn_mul(cx,cx), rn_mul(cy,cy)), rn_mul(cz,cz));

  // ---- 1: d2 of 32 points/lane (identical formula as validated) + top-2 ----
  float d2r[32];
  float e0 = INFINITY, e1 = INFINITY;
  #pragma unroll
  for (int s = 0; s < 32; ++s){
    int i = (w << 11) + (s << 6) + ln;
    float x = Xb[i], y = Yb[i], z = Zb[i];
    float n2 = rn_add(rn_add(rn_mul(x,x), rn_mul(y,y)), rn_mul(z,z));
    float e  = rn_add(rn_add(rn_mul(cx,x), rn_mul(cy,y)), rn_mul(cz,z));
    float d  = rn_sub(rn_add(cn2, n2), rn_add(e,e));
    d2r[s] = d;
    if (d < e1){ if (d < e0){ e1 = e0; e0 = d; } else e1 = d; }
  }

  // ---- 2: per-wave bitonic sort of e1 keys (ascending across lanes) ----
  {
    unsigned v = fkey(e1);
    #pragma unroll
    for (int k = 2; k <= 64; k <<= 1){
      #pragma unroll
      for (int j = k >> 1; j > 0; j >>= 1){
        unsigned o = (unsigned)__shfl_xor((int)v, j);
        bool keepmin = (((ln & k) == 0) == ((ln & j) == 0));
        unsigned mn = o < v ? o : v;
        unsigned mx = o < v ? v : o;
        v = keepmin ? mn : mx;
      }
    }
    if (ln < 16) sE[w*16 + ln] = v;
  }
  if (t == 0) s_cnt = 0;
  __syncthreads();

  // ---- 3: T = 16th smallest of sE[256] (all waves, redundant/uniform) ----
  unsigned T;
  {
    unsigned a0 = sE[ln*4+0], a1 = sE[ln*4+1], a2 = sE[ln*4+2], a3 = sE[ln*4+3];
    for (int r = 0; r < 16; ++r){
      unsigned m = a0 < a1 ? a0 : a1;
      unsigned m2 = a2 < a3 ? a2 : a3;
      m = m < m2 ? m : m2;
      #pragma unroll
      for (int off = 32; off >= 1; off >>= 1){
        unsigned o = (unsigned)__shfl_xor((int)m, off);
        m = o < m ? o : m;
      }
      T = m;
      unsigned long long msk = __ballot(a0 == m || a1 == m || a2 == m || a3 == m);
      int fl = __ffsll((long long)msk) - 1;
      if (ln == fl){
        if (a0 == m) a0 = 0xFFFFFFFFu;
        else if (a1 == m) a1 = 0xFFFFFFFFu;
        else if (a2 == m) a2 = 0xFFFFFFFFu;
        else a3 = 0xFFFFFFFFu;
      }
    }
  }

  // ---- 4: collect candidates key(d2) <= T ----
  #pragma unroll
  for (int s = 0; s < 32; ++s){
    if (fkey(d2r[s]) <= T){
      int i = (w << 11) + (s << 6) + ln;
      int p = atomicAdd(&s_cnt, 1);
      if (p < 512)
        s_cand[p] = ((unsigned long long)fkey(d2r[s]) << 32) | (unsigned)i;
    }
  }
  __syncthreads();

  // ---- 5: wave 0 selects exact top-32 by (d2, idx) ----
  if (w == 0){
    int C = s_cnt; if (C > 512) C = 512;
    int* kout = g_knn + (size_t)bg*KK;
    if (C <= 64){
      unsigned long long kk = (ln < C) ? s_cand[ln] : ~0ull;
      #pragma unroll
      for (int k = 2; k <= 64; k <<= 1){
        #pragma unroll
        for (int j = k >> 1; j > 0; j >>= 1){
          unsigned long long o = (unsigned long long)__shfl_xor((long long)kk, j);
          bool keepmin = (((ln & k) == 0) == ((ln & j) == 0));
          unsigned long long mn = o < kk ? o : kk;
          unsigned long long mx = o < kk ? kk : o;
          kk = keepmin ? mn : mx;
        }
      }
      if (ln < KK) kout[ln] = (int)(kk & 0xffffffffu);
    } else {
      unsigned long long md[8];
      #pragma unroll
      for (int j = 0; j < 8; ++j){
        int e = ln + (j << 6);
        md[j] = (e < C) ? s_cand[e] : ~0ull;
      }
      for (int r = 0; r < KK; ++r){
        unsigned long long bk = md[0];
        #pragma unroll
        for (int j = 1; j < 8; ++j) if (md[j] < bk) bk = md[j];
        #pragma unroll
        for (int off = 32; off >= 1; off >>= 1){
          unsigned long long o = (unsigned long long)__shfl_xor((long long)bk, off);
          if (o < bk) bk = o;
        }
        #pragma unroll
        for (int j = 0; j < 8; ++j) if (md[j] == bk) md[j] = ~0ull;  // keys unique
        if (ln == 0) kout[r] = (int)(bk & 0xffffffffu);
      }
    }
  }
}

// ---------------------------------------------------------------------------
// MLP 6->64->128->384 + maxpool over K. 1 block per (b,g), 256 threads.
// ---------------------------------------------------------------------------
__global__ __launch_bounds__(256) void k_mlp(const float* __restrict__ xyz,
                                             const float* __restrict__ feat,
                                             float* __restrict__ outPatch){
  const int bg = blockIdx.x;
  const int b  = bg >> 6;
  const int t  = threadIdx.x;
  const float* xb = xyz  + (size_t)b*NN*3;
  const float* fb = feat + (size_t)b*NN*3;

  __shared__ float h0[KK][8];
  __shared__ float h1[KK][68];
  __shared__ float h2[KK][132];
  __shared__ float pmax[4][DD];

  if (t < KK){
    int idx = g_knn[(size_t)bg*KK + t] & (NN - 1);   // defensive clamp (power of 2)
    const float* cp = g_center + (size_t)bg*3;
    h0[t][0] = rn_sub(xb[idx*3+0], cp[0]);
    h0[t][1] = rn_sub(xb[idx*3+1], cp[1]);
    h0[t][2] = rn_sub(xb[idx*3+2], cp[2]);
    h0[t][3] = fb[idx*3+0];
    h0[t][4] = fb[idx*3+1];
    h0[t][5] = fb[idx*3+2];
  }
  __syncthreads();

  { // L1: 32k x 64o, thread = (k, 8 o's)
    int k = t >> 3, ob = (t & 7) * 8;
    float acc[8];
    #pragma unroll
    for (int j = 0; j < 8; ++j) acc[j] = g_b1[ob + j];
    #pragma unroll
    for (int c = 0; c < 6; ++c){
      float a = h0[k][c];
      const float4* wr = (const float4*)(g_w1t + c*64 + ob);
      float4 wa = wr[0], wb = wr[1];
      acc[0] = fmaf(a, wa.x, acc[0]); acc[1] = fmaf(a, wa.y, acc[1]);
      acc[2] = fmaf(a, wa.z, acc[2]); acc[3] = fmaf(a, wa.w, acc[3]);
      acc[4] = fmaf(a, wb.x, acc[4]); acc[5] = fmaf(a, wb.y, acc[5]);
      acc[6] = fmaf(a, wb.z, acc[6]); acc[7] = fmaf(a, wb.w, acc[7]);
    }
    #pragma unroll
    for (int j = 0; j < 8; ++j) h1[k][ob + j] = fmaxf(acc[j], 0.f);
  }
  __syncthreads();

  { // L2: 32k x 128o, thread = (k, 16 o's)
    int k = t >> 3, ob = (t & 7) * 16;
    float acc[16];
    #pragma unroll
    for (int j = 0; j < 16; ++j) acc[j] = g_b2[ob + j];
    for (int c = 0; c < 64; ++c){
      float a = h1[k][c];
      const float4* wr = (const float4*)(g_w2t + c*128 + ob);
      #pragma unroll
      for (int q = 0; q < 4; ++q){
        float4 w4 = wr[q];
        acc[q*4+0] = fmaf(a, w4.x, acc[q*4+0]);
        acc[q*4+1] = fmaf(a, w4.y, acc[q*4+1]);
        acc[q*4+2] = fmaf(a, w4.z, acc[q*4+2]);
        acc[q*4+3] = fmaf(a, w4.w, acc[q*4+3]);
      }
    }
    #pragma unroll
    for (int j = 0; j < 16; ++j) h2[k][ob + j] = fmaxf(acc[j], 0.f);
  }
  __syncthreads();

  { // L3: 32k x 384o + partial max over k. wave wv owns k in [8wv,8wv+8).
    int wv = t >> 6, ln = t & 63;
    float acc[8][6];
    #pragma unroll
    for (int kk = 0; kk < 8; ++kk)
      #pragma unroll
      for (int j = 0; j < 6; ++j) acc[kk][j] = 0.f;
    for (int c = 0; c < 128; ++c){
      float hk[8];
      #pragma unroll
      for (int kk = 0; kk < 8; ++kk) hk[kk] = h2[wv*8 + kk][c];  // broadcast
      float wj[6];
      #pragma unroll
      for (int j = 0; j < 6; ++j) wj[j] = g_w3t[c*384 + ln + 64*j]; // coalesced
      #pragma unroll
      for (int kk = 0; kk < 8; ++kk)
        #pragma unroll
        for (int j = 0; j < 6; ++j) acc[kk][j] = fmaf(hk[kk], wj[j], acc[kk][j]);
    }
    #pragma unroll
    for (int j = 0; j < 6; ++j){
      float m = acc[0][j];
      #pragma unroll
      for (int kk = 1; kk < 8; ++kk) m = fmaxf(m, acc[kk][j]);
      pmax[wv][ln + 64*j] = m;
    }
  }
  __syncthreads();

  if (t < 128){
    #pragma unroll
    for (int s = 0; s < 3; ++s){
      int o = t + 128*s;
      float m = fmaxf(fmaxf(pmax[0][o], pmax[1][o]), fmaxf(pmax[2][o], pmax[3][o]));
      outPatch[(size_t)bg*DD + o] = m + g_b3[o];
    }
  }
}

// ---------------------------------------------------------------------------
extern "C" void kernel_launch(void* const* d_in, const int* in_sizes, int n_in,
                              void* d_out, int out_size, void* d_ws, size_t ws_size,
                              hipStream_t stream){
  (void)in_sizes; (void)n_in; (void)out_size; (void)d_ws; (void)ws_size;
  const float* xyz  = (const float*)d_in[0];
  const float* feat = (const float*)d_in[1];
  const float* w1 = (const float*)d_in[2];
  const float* g1 = (const float*)d_in[3];
  const float* b1 = (const float*)d_in[4];
  const float* m1 = (const float*)d_in[5];
  const float* v1 = (const float*)d_in[6];
  const float* w2 = (const float*)d_in[7];
  const float* g2 = (const float*)d_in[8];
  const float* b2 = (const float*)d_in[9];
  const float* m2 = (const float*)d_in[10];
  const float* v2 = (const float*)d_in[11];
  const float* w3 = (const float*)d_in[12];
  const float* g3 = (const float*)d_in[13];
  const float* b3 = (const float*)d_in[14];
  const float* m3 = (const float*)d_in[15];
  const float* v3 = (const float*)d_in[16];
  float* out = (float*)d_out;

  k_prep<<<64, 256, 0, stream>>>(w1,g1,b1,m1,v1, w2,g2,b2,m2,v2, w3,g3,b3,m3,v3);
  k_soa<<<(BB*NN)/256, 256, 0, stream>>>(xyz);
  k_zero<<<64, 256, 0, stream>>>();
  k_fps<<<BB*FPS_NBLK, 256, 0, stream>>>(out);
  k_knn<<<BB*GG, 1024, 0, stream>>>();
  k_mlp<<<BB*GG, 256, 0, stream>>>(xyz, feat, out + (size_t)BB*GG*3);
}

// Round 11
// 456.298 us; speedup vs baseline: 3.0758x; 1.2644x over previous
//
#include <hip/hip_runtime.h>
#include <hip/hip_bf16.h>

#define BB 32
#define NN 32768
#define GG 64
#define KK 32
#define DD 384
#define EPSF 1e-5f
#define FPS_NBLK 8          // blocks per batch for k_fps
#define FPS_SL   (NN/FPS_NBLK)   // 4096-point slice per block

__device__ __forceinline__ float rn_add(float a, float b){ return __fadd_rn(a,b); }
__device__ __forceinline__ float rn_sub(float a, float b){ return __fsub_rn(a,b); }
__device__ __forceinline__ float rn_mul(float a, float b){ return __fmul_rn(a,b); }

// monotone float->u32 map: preserves total order of finite floats.
// For d >= 0 (our case): result >= 0x80000000 -> composite key never 0.
__device__ __forceinline__ unsigned fkey(float d){
  unsigned u = __float_as_uint(d);
  return (u & 0x80000000u) ? ~u : (u | 0x80000000u);
}

#define REP16(X) X(0) X(1) X(2) X(3) X(4) X(5) X(6) X(7) \
                 X(8) X(9) X(10) X(11) X(12) X(13) X(14) X(15)

// ---- module-scope scratch: avoids any assumption about ws_size ------------
__device__ float g_center[BB*GG*3];     // 24 KB
__device__ int   g_knn[BB*GG*KK];       // 256 KB
__device__ float g_w1t[6*64];           // folded, transposed weights
__device__ float g_b1[64];
__device__ float g_w2t[64*128];
__device__ float g_b2[128];
__device__ float g_w3t[128*384];
__device__ float g_b3[384];
__device__ float g_X[BB*NN];            // 4 MB SoA coords (bit-exact copies)
__device__ float g_Y[BB*NN];            // 4 MB
__device__ float g_Z[BB*NN];            // 4 MB
__device__ float g_N2[BB*NN];           // 4 MB: n2 = ((x*x+y*y)+z*z), exact rn
__device__ unsigned long long g_part[BB*FPS_NBLK*GG];  // per-(b,sub,iter) keys

// ---------------------------------------------------------------------------
// One-shot AoS -> SoA repack (bit-exact copy) + n2 precompute (exact same
// rn sequence as the validated in-kernel computation -> bit-identical d2).
// ---------------------------------------------------------------------------
__global__ __launch_bounds__(256) void k_soa(const float* __restrict__ xyz){
  int tid = blockIdx.x * blockDim.x + threadIdx.x;   // 0 .. BB*NN-1
  int b = tid >> 15;                                  // NN = 2^15
  int p = tid & (NN - 1);
  const float* s = xyz + (size_t)b*NN*3 + (size_t)p*3;
  float x = s[0], y = s[1], z = s[2];
  g_X[tid] = x;
  g_Y[tid] = y;
  g_Z[tid] = z;
  g_N2[tid] = rn_add(rn_add(rn_mul(x,x), rn_mul(y,y)), rn_mul(z,z));
}

// zero the fps slots (every call: graph replays must be deterministic)
__global__ __launch_bounds__(256) void k_zero(void){
  int tid = blockIdx.x * blockDim.x + threadIdx.x;
  if (tid < BB*FPS_NBLK*GG) g_part[tid] = 0ull;
}

// ---------------------------------------------------------------------------
// Weight prep: fold BN (scale,shift) into transposed weights.
// ---------------------------------------------------------------------------
__global__ void k_prep(const float* __restrict__ w1, const float* __restrict__ g1, const float* __restrict__ b1, const float* __restrict__ m1, const float* __restrict__ v1,
                       const float* __restrict__ w2, const float* __restrict__ g2, const float* __restrict__ b2, const float* __restrict__ m2, const float* __restrict__ v2,
                       const float* __restrict__ w3, const float* __restrict__ g3, const float* __restrict__ b3, const float* __restrict__ m3, const float* __restrict__ v3){
  int tid = blockIdx.x * blockDim.x + threadIdx.x;
  int nt  = gridDim.x * blockDim.x;
  for (int e = tid; e < 64*6; e += nt){
    int c = e >> 6, o = e & 63;
    float s = g1[o] * rsqrtf(v1[o] + EPSF);
    g_w1t[e] = w1[o*6 + c] * s;
  }
  for (int o = tid; o < 64; o += nt){
    float s = g1[o] * rsqrtf(v1[o] + EPSF);
    g_b1[o] = b1[o] - m1[o]*s;
  }
  for (int e = tid; e < 64*128; e += nt){
    int c = e >> 7, o = e & 127;
    float s = g2[o] * rsqrtf(v2[o] + EPSF);
    g_w2t[e] = w2[o*64 + c] * s;
  }
  for (int o = tid; o < 128; o += nt){
    float s = g2[o] * rsqrtf(v2[o] + EPSF);
    g_b2[o] = b2[o] - m2[o]*s;
  }
  for (int e = tid; e < 384*128; e += nt){   // e = o*128+c (input-major)
    int o = e >> 7, c = e & 127;
    float s = g3[o] * rsqrtf(v3[o] + EPSF);
    g_w3t[c*384 + o] = w3[e] * s;
  }
  for (int o = tid; o < 384; o += nt){
    float s = g3[o] * rsqrtf(v3[o] + EPSF);
    g_b3[o] = b3[o] - m3[o]*s;
  }
}

// ---------------------------------------------------------------------------
// FPS v5 (validated r10): 8 blocks/batch x 256 threads, LDS-staged slice,
// atomicExch publish + parallel poll. ~2.3us/iter sync-latency floor.
// ---------------------------------------------------------------------------
__global__ __launch_bounds__(256)
void k_fps(float* __restrict__ outCenter){
  const int blk = blockIdx.x;
  const int b   = blk >> 3;          // batch
  const int sub = blk & 7;           // sub-block within batch
  const int t   = threadIdx.x;
  const int wv  = t >> 6, ln = t & 63;
  const int base = sub * FPS_SL;     // 4096-point slice
  const float* Xb = g_X + (size_t)b*NN;
  const float* Yb = g_Y + (size_t)b*NN;
  const float* Zb = g_Z + (size_t)b*NN;

  __shared__ float sx[FPS_SL], sy[FPS_SL], szz[FPS_SL];   // 48 KB
  __shared__ unsigned long long skey[4];
  __shared__ int s_far;

  #pragma unroll
  for (int i = 0; i < 16; ++i){
    int p = (i << 8) + t;
    sx[p]  = Xb[base + p];
    sy[p]  = Yb[base + p];
    szz[p] = Zb[base + p];
  }
  __syncthreads();

#define DD_DECL(i) float dd##i = 1e10f;
  REP16(DD_DECL)
#undef DD_DECL

  int far = 0;
  for (int it = 0; ; ++it){
    if (sub == 0 && t == 0){
      float cx = Xb[far], cy = Yb[far], cz = Zb[far];
      float* cw = g_center  + (size_t)(b*GG + it)*3;
      float* co = outCenter + (size_t)(b*GG + it)*3;
      cw[0] = cx; cw[1] = cy; cw[2] = cz;
      co[0] = cx; co[1] = cy; co[2] = cz;
    }
    if (it == GG - 1) break;

    float cx = Xb[far], cy = Yb[far], cz = Zb[far];   // broadcast loads (L2)
    unsigned long long bk = 0ull;
    // ascending i => ascending point idx; keys unique (idx embedded) so
    // max key == (max d, tie -> lowest idx) == numpy argmax.
#define DD_UPD(i) { \
    int p = (i << 8) + t; \
    float dx = rn_sub(sx[p], cx); \
    float dy = rn_sub(sy[p], cy); \
    float dz = rn_sub(szz[p], cz); \
    float s_ = rn_add(rn_add(rn_mul(dx,dx), rn_mul(dy,dy)), rn_mul(dz,dz)); \
    float d_ = fminf(dd##i, s_); \
    dd##i = d_; \
    unsigned long long k_ = ((unsigned long long)fkey(d_) << 32) \
                          | (unsigned)(0xFFFFFFFFu - (unsigned)(base + p)); \
    if (k_ > bk) bk = k_; }
    REP16(DD_UPD)
#undef DD_UPD

    #pragma unroll
    for (int off = 32; off >= 1; off >>= 1){
      unsigned long long o = (unsigned long long)__shfl_xor((long long)bk, off);
      if (o > bk) bk = o;
    }
    if (ln == 0) skey[wv] = bk;
    __syncthreads();
    if (wv == 0){
      unsigned long long m = (ln < 4) ? skey[ln] : 0ull;
      #pragma unroll
      for (int off = 1; off <= 2; off <<= 1){
        unsigned long long o = (unsigned long long)__shfl_xor((long long)m, off);
        if (o > m) m = o;
      }
      if (ln == 0)
        atomicExch(&g_part[(((b << 3) + sub) << 6) + it], m);
      unsigned long long k = 0ull;
      if (ln < 8){
        unsigned long long* p = &g_part[(((b << 3) + ln) << 6) + it];
        do { k = atomicAdd(p, 0ull); } while (k == 0ull);
      }
      #pragma unroll
      for (int off = 1; off <= 4; off <<= 1){
        unsigned long long o = (unsigned long long)__shfl_xor((long long)k, off);
        if (o > k) k = o;
      }
      if (ln == 0) s_far = (int)(0xFFFFFFFFu - (unsigned)(k & 0xFFFFFFFFu));
    }
    __syncthreads();
    far = s_far;
  }
}

// ---------------------------------------------------------------------------
// KNN v4: 256 threads (4 waves), 128 pts/thread via float4 + precomputed n2.
// r10 post-mortem: 16-wave blocks -> 27% occupancy, serial tails idle.
// Now 8 blocks/CU (all 2048 blocks resident), T found by SORT:
//   per-wave bitonic of e1-keys -> 16 smallest/wave -> bitonic-64 -> T=elem 15
//   (exact global 16th of 256 e1s; 16 threads x top-2 <= T => >=32 pts <= T).
// Phase 4 recomputes d2 (no d2 storage; order irrelevant - final selection
// sorts composite (d2,idx) keys == lax.top_k(-d2,K) exactly).
// ---------------------------------------------------------------------------
__global__ __launch_bounds__(256) void k_knn(void){
  const int bg = blockIdx.x;        // b*64+g
  const int b  = bg >> 6;
  const int t  = threadIdx.x;       // 0..255
  const int w  = t >> 6;            // wave 0..3
  const int ln = t & 63;
  const float4* X4 = (const float4*)(g_X  + (size_t)b*NN);
  const float4* Y4 = (const float4*)(g_Y  + (size_t)b*NN);
  const float4* Z4 = (const float4*)(g_Z  + (size_t)b*NN);
  const float4* N4 = (const float4*)(g_N2 + (size_t)b*NN);

  __shared__ unsigned sE[64];                // 4 waves x 16 smallest e1-keys
  __shared__ unsigned long long s_cand[512]; // candidate (key,idx)
  __shared__ int s_cnt;

  const float* cp = g_center + (size_t)bg*3;
  float cx = cp[0], cy = cp[1], cz = cp[2];
  float cn2 = rn_add(rn_add(rn_mul(cx,cx), rn_mul(cy,cy)), rn_mul(cz,cz));

  // ---- 1: scan 128 pts/thread, track 2 smallest (values only) ----
  float e0 = INFINITY, e1 = INFINITY;
  #pragma unroll 2
  for (int s = 0; s < 32; ++s){
    int q = (s << 8) + t;            // float4 index; points 4q..4q+3
    float4 x = X4[q], y = Y4[q], z = Z4[q], n = N4[q];
    #define D2C(c) { \
      float e = rn_add(rn_add(rn_mul(cx,x.c), rn_mul(cy,y.c)), rn_mul(cz,z.c)); \
      float d = rn_sub(rn_add(cn2, n.c), rn_add(e,e)); \
      if (d < e1){ if (d < e0){ e1 = e0; e0 = d; } else e1 = d; } }
    D2C(x) D2C(y) D2C(z) D2C(w)
    #undef D2C
  }

  // ---- 2: per-wave bitonic sort of e1-keys; 16 smallest -> sE ----
  {
    unsigned v = fkey(e1);
    #pragma unroll
    for (int k = 2; k <= 64; k <<= 1){
      #pragma unroll
      for (int j = k >> 1; j > 0; j >>= 1){
        unsigned o = (unsigned)__shfl_xor((int)v, j);
        bool keepmin = (((ln & k) == 0) == ((ln & j) == 0));
        unsigned mn = o < v ? o : v;
        unsigned mx = o < v ? v : o;
        v = keepmin ? mn : mx;
      }
    }
    if (ln < 16) sE[w*16 + ln] = v;
  }
  if (t == 0) s_cnt = 0;
  __syncthreads();

  // ---- 3: T = exact 16th smallest of the 256 e1s. Global top-16 is
  // contained in the union of per-wave top-16s => sort sE[64], take [15].
  unsigned T;
  {
    unsigned v = sE[ln];
    #pragma unroll
    for (int k = 2; k <= 64; k <<= 1){
      #pragma unroll
      for (int j = k >> 1; j > 0; j >>= 1){
        unsigned o = (unsigned)__shfl_xor((int)v, j);
        bool keepmin = (((ln & k) == 0) == ((ln & j) == 0));
        unsigned mn = o < v ? o : v;
        unsigned mx = o < v ? v : o;
        v = keepmin ? mn : mx;
      }
    }
    T = (unsigned)__shfl((int)v, 15);
  }

  // ---- 4: recompute d2, collect candidates key(d2) <= T ----
  #pragma unroll 2
  for (int s = 0; s < 32; ++s){
    int q = (s << 8) + t;
    float4 x = X4[q], y = Y4[q], z = Z4[q], n = N4[q];
    #define COLC(c, kk) { \
      float e = rn_add(rn_add(rn_mul(cx,x.c), rn_mul(cy,y.c)), rn_mul(cz,z.c)); \
      float d = rn_sub(rn_add(cn2, n.c), rn_add(e,e)); \
      unsigned fk = fkey(d); \
      if (fk <= T){ \
        int p = atomicAdd(&s_cnt, 1); \
        if (p < 512) \
          s_cand[p] = ((unsigned long long)fk << 32) | (unsigned)((q<<2)+kk); } }
    COLC(x,0) COLC(y,1) COLC(z,2) COLC(w,3)
    #undef COLC
  }
  __syncthreads();

  // ---- 5: wave 0 selects exact top-32 by (d2, idx) ----
  if (w == 0){
    int C = s_cnt; if (C > 512) C = 512;
    int* kout = g_knn + (size_t)bg*KK;
    if (C <= 64){
      unsigned long long kk = (ln < C) ? s_cand[ln] : ~0ull;
      #pragma unroll
      for (int k = 2; k <= 64; k <<= 1){
        #pragma unroll
        for (int j = k >> 1; j > 0; j >>= 1){
          unsigned long long o = (unsigned long long)__shfl_xor((long long)kk, j);
          bool keepmin = (((ln & k) == 0) == ((ln & j) == 0));
          unsigned long long mn = o < kk ? o : kk;
          unsigned long long mx = o < kk ? kk : o;
          kk = keepmin ? mn : mx;
        }
      }
      if (ln < KK) kout[ln] = (int)(kk & 0xffffffffu);
    } else {
      unsigned long long md[8];
      #pragma unroll
      for (int j = 0; j < 8; ++j){
        int e = ln + (j << 6);
        md[j] = (e < C) ? s_cand[e] : ~0ull;
      }
      for (int r = 0; r < KK; ++r){
        unsigned long long bk = md[0];
        #pragma unroll
        for (int j = 1; j < 8; ++j) if (md[j] < bk) bk = md[j];
        #pragma unroll
        for (int off = 32; off >= 1; off >>= 1){
          unsigned long long o = (unsigned long long)__shfl_xor((long long)bk, off);
          if (o < bk) bk = o;
        }
        #pragma unroll
        for (int j = 0; j < 8; ++j) if (md[j] == bk) md[j] = ~0ull;  // keys unique
        if (ln == 0) kout[r] = (int)(bk & 0xffffffffu);
      }
    }
  }
}

// ---------------------------------------------------------------------------
// MLP 6->64->128->384 + maxpool over K. 1 block per (b,g), 256 threads.
// ---------------------------------------------------------------------------
__global__ __launch_bounds__(256) void k_mlp(const float* __restrict__ xyz,
                                             const float* __restrict__ feat,
                                             float* __restrict__ outPatch){
  const int bg = blockIdx.x;
  const int b  = bg >> 6;
  const int t  = threadIdx.x;
  const float* xb = xyz  + (size_t)b*NN*3;
  const float* fb = feat + (size_t)b*NN*3;

  __shared__ float h0[KK][8];
  __shared__ float h1[KK][68];
  __shared__ float h2[KK][132];
  __shared__ float pmax[4][DD];

  if (t < KK){
    int idx = g_knn[(size_t)bg*KK + t] & (NN - 1);   // defensive clamp (power of 2)
    const float* cp = g_center + (size_t)bg*3;
    h0[t][0] = rn_sub(xb[idx*3+0], cp[0]);
    h0[t][1] = rn_sub(xb[idx*3+1], cp[1]);
    h0[t][2] = rn_sub(xb[idx*3+2], cp[2]);
    h0[t][3] = fb[idx*3+0];
    h0[t][4] = fb[idx*3+1];
    h0[t][5] = fb[idx*3+2];
  }
  __syncthreads();

  { // L1: 32k x 64o, thread = (k, 8 o's)
    int k = t >> 3, ob = (t & 7) * 8;
    float acc[8];
    #pragma unroll
    for (int j = 0; j < 8; ++j) acc[j] = g_b1[ob + j];
    #pragma unroll
    for (int c = 0; c < 6; ++c){
      float a = h0[k][c];
      const float4* wr = (const float4*)(g_w1t + c*64 + ob);
      float4 wa = wr[0], wb = wr[1];
      acc[0] = fmaf(a, wa.x, acc[0]); acc[1] = fmaf(a, wa.y, acc[1]);
      acc[2] = fmaf(a, wa.z, acc[2]); acc[3] = fmaf(a, wa.w, acc[3]);
      acc[4] = fmaf(a, wb.x, acc[4]); acc[5] = fmaf(a, wb.y, acc[5]);
      acc[6] = fmaf(a, wb.z, acc[6]); acc[7] = fmaf(a, wb.w, acc[7]);
    }
    #pragma unroll
    for (int j = 0; j < 8; ++j) h1[k][ob + j] = fmaxf(acc[j], 0.f);
  }
  __syncthreads();

  { // L2: 32k x 128o, thread = (k, 16 o's)
    int k = t >> 3, ob = (t & 7) * 16;
    float acc[16];
    #pragma unroll
    for (int j = 0; j < 16; ++j) acc[j] = g_b2[ob + j];
    for (int c = 0; c < 64; ++c){
      float a = h1[k][c];
      const float4* wr = (const float4*)(g_w2t + c*128 + ob);
      #pragma unroll
      for (int q = 0; q < 4; ++q){
        float4 w4 = wr[q];
        acc[q*4+0] = fmaf(a, w4.x, acc[q*4+0]);
        acc[q*4+1] = fmaf(a, w4.y, acc[q*4+1]);
        acc[q*4+2] = fmaf(a, w4.z, acc[q*4+2]);
        acc[q*4+3] = fmaf(a, w4.w, acc[q*4+3]);
      }
    }
    #pragma unroll
    for (int j = 0; j < 16; ++j) h2[k][ob + j] = fmaxf(acc[j], 0.f);
  }
  __syncthreads();

  { // L3: 32k x 384o + partial max over k. wave wv owns k in [8wv,8wv+8).
    int wv = t >> 6, ln = t & 63;
    float acc[8][6];
    #pragma unroll
    for (int kk = 0; kk < 8; ++kk)
      #pragma unroll
      for (int j = 0; j < 6; ++j) acc[kk][j] = 0.f;
    for (int c = 0; c < 128; ++c){
      float hk[8];
      #pragma unroll
      for (int kk = 0; kk < 8; ++kk) hk[kk] = h2[wv*8 + kk][c];  // broadcast
      float wj[6];
      #pragma unroll
      for (int j = 0; j < 6; ++j) wj[j] = g_w3t[c*384 + ln + 64*j]; // coalesced
      #pragma unroll
      for (int kk = 0; kk < 8; ++kk)
        #pragma unroll
        for (int j = 0; j < 6; ++j) acc[kk][j] = fmaf(hk[kk], wj[j], acc[kk][j]);
    }
    #pragma unroll
    for (int j = 0; j < 6; ++j){
      float m = acc[0][j];
      #pragma unroll
      for (int kk = 1; kk < 8; ++kk) m = fmaxf(m, acc[kk][j]);
      pmax[wv][ln + 64*j] = m;
    }
  }
  __syncthreads();

  if (t < 128){
    #pragma unroll
    for (int s = 0; s < 3; ++s){
      int o = t + 128*s;
      float m = fmaxf(fmaxf(pmax[0][o], pmax[1][o]), fmaxf(pmax[2][o], pmax[3][o]));
      outPatch[(size_t)bg*DD + o] = m + g_b3[o];
    }
  }
}

// ---------------------------------------------------------------------------
extern "C" void kernel_launch(void* const* d_in, const int* in_sizes, int n_in,
                              void* d_out, int out_size, void* d_ws, size_t ws_size,
                              hipStream_t stream){
  (void)in_sizes; (void)n_in; (void)out_size; (void)d_ws; (void)ws_size;
  const float* xyz  = (const float*)d_in[0];
  const float* feat = (const float*)d_in[1];
  const float* w1 = (const float*)d_in[2];
  const float* g1 = (const float*)d_in[3];
  const float* b1 = (const float*)d_in[4];
  const float* m1 = (const float*)d_in[5];
  const float* v1 = (const float*)d_in[6];
  const float* w2 = (const float*)d_in[7];
  const float* g2 = (const float*)d_in[8];
  const float* b2 = (const float*)d_in[9];
  const float* m2 = (const float*)d_in[10];
  const float* v2 = (const float*)d_in[11];
  const float* w3 = (const float*)d_in[12];
  const float* g3 = (const float*)d_in[13];
  const float* b3 = (const float*)d_in[14];
  const float* m3 = (const float*)d_in[15];
  const float* v3 = (const float*)d_in[16];
  float* out = (float*)d_out;

  k_prep<<<64, 256, 0, stream>>>(w1,g1,b1,m1,v1, w2,g2,b2,m2,v2, w3,g3,b3,m3,v3);
  k_soa<<<(BB*NN)/256, 256, 0, stream>>>(xyz);
  k_zero<<<64, 256, 0, stream>>>();
  k_fps<<<BB*FPS_NBLK, 256, 0, stream>>>(out);
  k_knn<<<BB*GG, 256, 0, stream>>>();
  k_mlp<<<BB*GG, 256, 0, stream>>>(xyz, feat, out + (size_t)BB*GG*3);
}

// Round 12
// 300.861 us; speedup vs baseline: 4.6649x; 1.5166x over previous
//
#include <hip/hip_runtime.h>
#include <hip/hip_bf16.h>

#define BB 32
#define NN 32768
#define GG 64
#define KK 32
#define DD 384
#define EPSF 1e-5f
#define FPS_NBLK 8          // blocks per batch for k_fps
#define FPS_SL   (NN/FPS_NBLK)   // 4096-point slice per block

typedef __attribute__((ext_vector_type(8))) short short8;
typedef __attribute__((ext_vector_type(4))) float f32x4;

__device__ __forceinline__ float rn_add(float a, float b){ return __fadd_rn(a,b); }
__device__ __forceinline__ float rn_sub(float a, float b){ return __fsub_rn(a,b); }
__device__ __forceinline__ float rn_mul(float a, float b){ return __fmul_rn(a,b); }

// monotone float->u32 map: preserves total order of finite floats.
__device__ __forceinline__ unsigned fkey(float d){
  unsigned u = __float_as_uint(d);
  return (u & 0x80000000u) ? ~u : (u | 0x80000000u);
}

// f32 -> bf16 bits, round-to-nearest-even
__device__ __forceinline__ unsigned short f2bf(float f){
  unsigned u = __float_as_uint(f);
  unsigned r = (u + 0x7FFFu + ((u >> 16) & 1u)) >> 16;
  return (unsigned short)r;
}

#define REP16(X) X(0) X(1) X(2) X(3) X(4) X(5) X(6) X(7) \
                 X(8) X(9) X(10) X(11) X(12) X(13) X(14) X(15)

// ---- module-scope scratch ------------------------------------------------
__device__ float g_center[BB*GG*3];
__device__ int   g_knn[BB*GG*KK];
__device__ float g_w1t[6*64];
__device__ float g_b1[64];
__device__ float g_b2[128];
__device__ float g_b3[384];
__device__ __align__(16) unsigned short g_w2f[8*2*64*8];    // w2 MFMA frags (16 KB)
__device__ __align__(16) unsigned short g_w3f[24*4*64*8];   // w3 MFMA frags (96 KB)
__device__ float g_X[BB*NN];
__device__ float g_Y[BB*NN];
__device__ float g_Z[BB*NN];
__device__ float g_N2[BB*NN];
__device__ unsigned long long g_part[BB*FPS_NBLK*GG];

// ---------------------------------------------------------------------------
// One-shot AoS -> SoA repack + n2 precompute (bit-exact rn sequence).
// ---------------------------------------------------------------------------
__global__ __launch_bounds__(256) void k_soa(const float* __restrict__ xyz){
  int tid = blockIdx.x * blockDim.x + threadIdx.x;
  int b = tid >> 15;
  int p = tid & (NN - 1);
  const float* s = xyz + (size_t)b*NN*3 + (size_t)p*3;
  float x = s[0], y = s[1], z = s[2];
  g_X[tid] = x;
  g_Y[tid] = y;
  g_Z[tid] = z;
  g_N2[tid] = rn_add(rn_add(rn_mul(x,x), rn_mul(y,y)), rn_mul(z,z));
}

__global__ __launch_bounds__(256) void k_zero(void){
  int tid = blockIdx.x * blockDim.x + threadIdx.x;
  if (tid < BB*FPS_NBLK*GG) g_part[tid] = 0ull;
}

// ---------------------------------------------------------------------------
// Weight prep: fold BN; w1 transposed f32; w2/w3 packed as bf16 MFMA B-frags.
// Frag layout (assumed, SAME convention used for A-side LDS reads, so any
// k-mapping discrepancy vs HW cancels in the contraction):
//   B[k][j], j = ct*16 + (lane&15), k = kt*32 + (lane>>4)*8 + e
//   stored at ((ct*KT + kt)*64 + lane)*8 + e.
// ---------------------------------------------------------------------------
__global__ void k_prep(const float* __restrict__ w1, const float* __restrict__ g1, const float* __restrict__ b1, const float* __restrict__ m1, const float* __restrict__ v1,
                       const float* __restrict__ w2, const float* __restrict__ g2, const float* __restrict__ b2, const float* __restrict__ m2, const float* __restrict__ v2,
                       const float* __restrict__ w3, const float* __restrict__ g3, const float* __restrict__ b3, const float* __restrict__ m3, const float* __restrict__ v3){
  int tid = blockIdx.x * blockDim.x + threadIdx.x;
  int nt  = gridDim.x * blockDim.x;
  for (int e = tid; e < 64*6; e += nt){
    int c = e >> 6, o = e & 63;
    float s = g1[o] * rsqrtf(v1[o] + EPSF);
    g_w1t[e] = w1[o*6 + c] * s;
  }
  for (int o = tid; o < 64; o += nt){
    float s = g1[o] * rsqrtf(v1[o] + EPSF);
    g_b1[o] = b1[o] - m1[o]*s;
  }
  for (int o = tid; o < 128; o += nt){
    float s = g2[o] * rsqrtf(v2[o] + EPSF);
    g_b2[o] = b2[o] - m2[o]*s;
  }
  for (int o = tid; o < 384; o += nt){
    float s = g3[o] * rsqrtf(v3[o] + EPSF);
    g_b3[o] = b3[o] - m3[o]*s;
  }
  // w2 frags: 8 col-tiles x 2 ksteps: idx = ct*1024 + kt*512 + l*8 + e
  for (int idx = tid; idx < 8192; idx += nt){
    int e  = idx & 7;
    int l  = (idx >> 3) & 63;
    int kt = (idx >> 9) & 1;
    int ct = idx >> 10;
    int j  = ct*16 + (l & 15);
    int k  = kt*32 + ((l >> 4) << 3) + e;
    float s = g2[j] * rsqrtf(v2[j] + EPSF);
    g_w2f[idx] = f2bf(w2[j*64 + k] * s);
  }
  // w3 frags: 24 col-tiles x 4 ksteps: idx = ct*2048 + kt*512 + l*8 + e
  for (int idx = tid; idx < 49152; idx += nt){
    int e  = idx & 7;
    int l  = (idx >> 3) & 63;
    int kt = (idx >> 9) & 3;
    int ct = idx >> 11;
    int j  = ct*16 + (l & 15);
    int k  = kt*32 + ((l >> 4) << 3) + e;
    float s = g3[j] * rsqrtf(v3[j] + EPSF);
    g_w3f[idx] = f2bf(w3[j*128 + k] * s);
  }
}

// ---------------------------------------------------------------------------
// FPS v5 (validated r10): 8 blocks/batch x 256 threads, LDS-staged slice,
// atomicExch publish + parallel poll.
// ---------------------------------------------------------------------------
__global__ __launch_bounds__(256)
void k_fps(float* __restrict__ outCenter){
  const int blk = blockIdx.x;
  const int b   = blk >> 3;
  const int sub = blk & 7;
  const int t   = threadIdx.x;
  const int wv  = t >> 6, ln = t & 63;
  const int base = sub * FPS_SL;
  const float* Xb = g_X + (size_t)b*NN;
  const float* Yb = g_Y + (size_t)b*NN;
  const float* Zb = g_Z + (size_t)b*NN;

  __shared__ float sx[FPS_SL], sy[FPS_SL], szz[FPS_SL];
  __shared__ unsigned long long skey[4];
  __shared__ int s_far;

  #pragma unroll
  for (int i = 0; i < 16; ++i){
    int p = (i << 8) + t;
    sx[p]  = Xb[base + p];
    sy[p]  = Yb[base + p];
    szz[p] = Zb[base + p];
  }
  __syncthreads();

#define DD_DECL(i) float dd##i = 1e10f;
  REP16(DD_DECL)
#undef DD_DECL

  int far = 0;
  for (int it = 0; ; ++it){
    if (sub == 0 && t == 0){
      float cx = Xb[far], cy = Yb[far], cz = Zb[far];
      float* cw = g_center  + (size_t)(b*GG + it)*3;
      float* co = outCenter + (size_t)(b*GG + it)*3;
      cw[0] = cx; cw[1] = cy; cw[2] = cz;
      co[0] = cx; co[1] = cy; co[2] = cz;
    }
    if (it == GG - 1) break;

    float cx = Xb[far], cy = Yb[far], cz = Zb[far];
    unsigned long long bk = 0ull;
#define DD_UPD(i) { \
    int p = (i << 8) + t; \
    float dx = rn_sub(sx[p], cx); \
    float dy = rn_sub(sy[p], cy); \
    float dz = rn_sub(szz[p], cz); \
    float s_ = rn_add(rn_add(rn_mul(dx,dx), rn_mul(dy,dy)), rn_mul(dz,dz)); \
    float d_ = fminf(dd##i, s_); \
    dd##i = d_; \
    unsigned long long k_ = ((unsigned long long)fkey(d_) << 32) \
                          | (unsigned)(0xFFFFFFFFu - (unsigned)(base + p)); \
    if (k_ > bk) bk = k_; }
    REP16(DD_UPD)
#undef DD_UPD

    #pragma unroll
    for (int off = 32; off >= 1; off >>= 1){
      unsigned long long o = (unsigned long long)__shfl_xor((long long)bk, off);
      if (o > bk) bk = o;
    }
    if (ln == 0) skey[wv] = bk;
    __syncthreads();
    if (wv == 0){
      unsigned long long m = (ln < 4) ? skey[ln] : 0ull;
      #pragma unroll
      for (int off = 1; off <= 2; off <<= 1){
        unsigned long long o = (unsigned long long)__shfl_xor((long long)m, off);
        if (o > m) m = o;
      }
      if (ln == 0)
        atomicExch(&g_part[(((b << 3) + sub) << 6) + it], m);
      unsigned long long k = 0ull;
      if (ln < 8){
        unsigned long long* p = &g_part[(((b << 3) + ln) << 6) + it];
        do { k = atomicAdd(p, 0ull); } while (k == 0ull);
      }
      #pragma unroll
      for (int off = 1; off <= 4; off <<= 1){
        unsigned long long o = (unsigned long long)__shfl_xor((long long)k, off);
        if (o > k) k = o;
      }
      if (ln == 0) s_far = (int)(0xFFFFFFFFu - (unsigned)(k & 0xFFFFFFFFu));
    }
    __syncthreads();
    far = s_far;
  }
}

// ---------------------------------------------------------------------------
// KNN v4 (validated r11): 256 threads, float4 + precomputed n2, sort-based T.
// ---------------------------------------------------------------------------
__global__ __launch_bounds__(256) void k_knn(void){
  const int bg = blockIdx.x;
  const int b  = bg >> 6;
  const int t  = threadIdx.x;
  const int w  = t >> 6;
  const int ln = t & 63;
  const float4* X4 = (const float4*)(g_X  + (size_t)b*NN);
  const float4* Y4 = (const float4*)(g_Y  + (size_t)b*NN);
  const float4* Z4 = (const float4*)(g_Z  + (size_t)b*NN);
  const float4* N4 = (const float4*)(g_N2 + (size_t)b*NN);

  __shared__ unsigned sE[64];
  __shared__ unsigned long long s_cand[512];
  __shared__ int s_cnt;

  const float* cp = g_center + (size_t)bg*3;
  float cx = cp[0], cy = cp[1], cz = cp[2];
  float cn2 = rn_add(rn_add(rn_mul(cx,cx), rn_mul(cy,cy)), rn_mul(cz,cz));

  float e0 = INFINITY, e1 = INFINITY;
  #pragma unroll 2
  for (int s = 0; s < 32; ++s){
    int q = (s << 8) + t;
    float4 x = X4[q], y = Y4[q], z = Z4[q], n = N4[q];
    #define D2C(c) { \
      float e = rn_add(rn_add(rn_mul(cx,x.c), rn_mul(cy,y.c)), rn_mul(cz,z.c)); \
      float d = rn_sub(rn_add(cn2, n.c), rn_add(e,e)); \
      if (d < e1){ if (d < e0){ e1 = e0; e0 = d; } else e1 = d; } }
    D2C(x) D2C(y) D2C(z) D2C(w)
    #undef D2C
  }

  {
    unsigned v = fkey(e1);
    #pragma unroll
    for (int k = 2; k <= 64; k <<= 1){
      #pragma unroll
      for (int j = k >> 1; j > 0; j >>= 1){
        unsigned o = (unsigned)__shfl_xor((int)v, j);
        bool keepmin = (((ln & k) == 0) == ((ln & j) == 0));
        unsigned mn = o < v ? o : v;
        unsigned mx = o < v ? v : o;
        v = keepmin ? mn : mx;
      }
    }
    if (ln < 16) sE[w*16 + ln] = v;
  }
  if (t == 0) s_cnt = 0;
  __syncthreads();

  unsigned T;
  {
    unsigned v = sE[ln];
    #pragma unroll
    for (int k = 2; k <= 64; k <<= 1){
      #pragma unroll
      for (int j = k >> 1; j > 0; j >>= 1){
        unsigned o = (unsigned)__shfl_xor((int)v, j);
        bool keepmin = (((ln & k) == 0) == ((ln & j) == 0));
        unsigned mn = o < v ? o : v;
        unsigned mx = o < v ? v : o;
        v = keepmin ? mn : mx;
      }
    }
    T = (unsigned)__shfl((int)v, 15);
  }

  #pragma unroll 2
  for (int s = 0; s < 32; ++s){
    int q = (s << 8) + t;
    float4 x = X4[q], y = Y4[q], z = Z4[q], n = N4[q];
    #define COLC(c, kk) { \
      float e = rn_add(rn_add(rn_mul(cx,x.c), rn_mul(cy,y.c)), rn_mul(cz,z.c)); \
      float d = rn_sub(rn_add(cn2, n.c), rn_add(e,e)); \
      unsigned fk = fkey(d); \
      if (fk <= T){ \
        int p = atomicAdd(&s_cnt, 1); \
        if (p < 512) \
          s_cand[p] = ((unsigned long long)fk << 32) | (unsigned)((q<<2)+kk); } }
    COLC(x,0) COLC(y,1) COLC(z,2) COLC(w,3)
    #undef COLC
  }
  __syncthreads();

  if (w == 0){
    int C = s_cnt; if (C > 512) C = 512;
    int* kout = g_knn + (size_t)bg*KK;
    if (C <= 64){
      unsigned long long kk = (ln < C) ? s_cand[ln] : ~0ull;
      #pragma unroll
      for (int k = 2; k <= 64; k <<= 1){
        #pragma unroll
        for (int j = k >> 1; j > 0; j >>= 1){
          unsigned long long o = (unsigned long long)__shfl_xor((long long)kk, j);
          bool keepmin = (((ln & k) == 0) == ((ln & j) == 0));
          unsigned long long mn = o < kk ? o : kk;
          unsigned long long mx = o < kk ? kk : o;
          kk = keepmin ? mn : mx;
        }
      }
      if (ln < KK) kout[ln] = (int)(kk & 0xffffffffu);
    } else {
      unsigned long long md[8];
      #pragma unroll
      for (int j = 0; j < 8; ++j){
        int e = ln + (j << 6);
        md[j] = (e < C) ? s_cand[e] : ~0ull;
      }
      for (int r = 0; r < KK; ++r){
        unsigned long long bk = md[0];
        #pragma unroll
        for (int j = 1; j < 8; ++j) if (md[j] < bk) bk = md[j];
        #pragma unroll
        for (int off = 32; off >= 1; off >>= 1){
          unsigned long long o = (unsigned long long)__shfl_xor((long long)bk, off);
          if (o < bk) bk = o;
        }
        #pragma unroll
        for (int j = 0; j < 8; ++j) if (md[j] == bk) md[j] = ~0ull;
        if (ln == 0) kout[r] = (int)(bk & 0xffffffffu);
      }
    }
  }
}

// ---------------------------------------------------------------------------
// MLP v2: L1 VALU (K=6); L2/L3 via mfma_f32_16x16x32_bf16.
// A-frags from LDS bf16 (row pad -> 16B-aligned ds_read_b128, 2-way banks);
// B-frags pre-packed by k_prep (same k-mapping convention as A => any
// HW-mapping discrepancy permutes the contraction identically on both sides
// and cancels). C/D mapping (HW-verified m89): col=lane&15, row=(lane>>4)*4+reg.
// Row permutations are harmless: rows = points, epilogue max-pools all 32.
// ---------------------------------------------------------------------------
__global__ __launch_bounds__(256) void k_mlp(const float* __restrict__ xyz,
                                             const float* __restrict__ feat,
                                             float* __restrict__ outPatch){
  const int bg = blockIdx.x;
  const int b  = bg >> 6;
  const int t  = threadIdx.x;
  const int w  = t >> 6;
  const int ln = t & 63;
  const float* xb = xyz  + (size_t)b*NN*3;
  const float* fb = feat + (size_t)b*NN*3;

  __shared__ float h0[KK][8];                            // 1 KB
  __shared__ __align__(16) unsigned short h1b[KK][72];   // 4.5 KB (64+8 pad)
  __shared__ __align__(16) unsigned short h2b[KK][136];  // 8.5 KB (128+8 pad)

  if (t < KK){
    int idx = g_knn[(size_t)bg*KK + t] & (NN - 1);
    const float* cp = g_center + (size_t)bg*3;
    h0[t][0] = rn_sub(xb[idx*3+0], cp[0]);
    h0[t][1] = rn_sub(xb[idx*3+1], cp[1]);
    h0[t][2] = rn_sub(xb[idx*3+2], cp[2]);
    h0[t][3] = fb[idx*3+0];
    h0[t][4] = fb[idx*3+1];
    h0[t][5] = fb[idx*3+2];
  }
  __syncthreads();

  { // L1: thread = (point p = t>>3, octet ob = (t&7)*8), f32, relu -> bf16 LDS
    int p = t >> 3, ob = (t & 7) * 8;
    float acc[8];
    #pragma unroll
    for (int j = 0; j < 8; ++j) acc[j] = g_b1[ob + j];
    #pragma unroll
    for (int c = 0; c < 6; ++c){
      float a = h0[p][c];
      const float4* wr = (const float4*)(g_w1t + c*64 + ob);
      float4 wa = wr[0], wb = wr[1];
      acc[0] = fmaf(a, wa.x, acc[0]); acc[1] = fmaf(a, wa.y, acc[1]);
      acc[2] = fmaf(a, wa.z, acc[2]); acc[3] = fmaf(a, wa.w, acc[3]);
      acc[4] = fmaf(a, wb.x, acc[4]); acc[5] = fmaf(a, wb.y, acc[5]);
      acc[6] = fmaf(a, wb.z, acc[6]); acc[7] = fmaf(a, wb.w, acc[7]);
    }
    short8 v;
    #pragma unroll
    for (int j = 0; j < 8; ++j) v[j] = (short)f2bf(fmaxf(acc[j], 0.f));
    *reinterpret_cast<short8*>(&h1b[p][ob]) = v;
  }
  __syncthreads();

  // ---- L2: h2 = relu(h1 @ W2 + b2), M=32 N=128 K=64; wave w -> col-tiles 2w,2w+1
  {
    f32x4 a00 = {0,0,0,0}, a01 = {0,0,0,0}, a10 = {0,0,0,0}, a11 = {0,0,0,0};
    const int g8 = (ln >> 4) << 3;
    #pragma unroll
    for (int kk = 0; kk < 2; ++kk){
      short8 A0 = *reinterpret_cast<const short8*>(&h1b[(ln & 15)][kk*32 + g8]);
      short8 A1 = *reinterpret_cast<const short8*>(&h1b[16 + (ln & 15)][kk*32 + g8]);
      short8 B0 = *reinterpret_cast<const short8*>(&g_w2f[(((2*w+0)*2 + kk)*64 + ln)*8]);
      short8 B1 = *reinterpret_cast<const short8*>(&g_w2f[(((2*w+1)*2 + kk)*64 + ln)*8]);
      a00 = __builtin_amdgcn_mfma_f32_16x16x32_bf16(A0, B0, a00, 0, 0, 0);
      a01 = __builtin_amdgcn_mfma_f32_16x16x32_bf16(A1, B0, a01, 0, 0, 0);
      a10 = __builtin_amdgcn_mfma_f32_16x16x32_bf16(A0, B1, a10, 0, 0, 0);
      a11 = __builtin_amdgcn_mfma_f32_16x16x32_bf16(A1, B1, a11, 0, 0, 0);
    }
    int col0 = (2*w)*16 + (ln & 15);
    int col1 = col0 + 16;
    float bz0 = g_b2[col0], bz1 = g_b2[col1];
    int r0 = (ln >> 4) << 2;
    #pragma unroll
    for (int r = 0; r < 4; ++r){
      h2b[r0 + r][col0]      = f2bf(fmaxf(a00[r] + bz0, 0.f));
      h2b[16 + r0 + r][col0] = f2bf(fmaxf(a01[r] + bz0, 0.f));
      h2b[r0 + r][col1]      = f2bf(fmaxf(a10[r] + bz1, 0.f));
      h2b[16 + r0 + r][col1] = f2bf(fmaxf(a11[r] + bz1, 0.f));
    }
  }
  __syncthreads();

  // ---- L3: out = max_rows(h2 @ W3) + b3, M=32 N=384 K=128; wave w -> 6 col-tiles
  {
    f32x4 acc3[6][2];
    #pragma unroll
    for (int ci = 0; ci < 6; ++ci){
      acc3[ci][0] = (f32x4){0,0,0,0};
      acc3[ci][1] = (f32x4){0,0,0,0};
    }
    const int g8 = (ln >> 4) << 3;
    #pragma unroll
    for (int kk = 0; kk < 4; ++kk){
      short8 A0 = *reinterpret_cast<const short8*>(&h2b[(ln & 15)][kk*32 + g8]);
      short8 A1 = *reinterpret_cast<const short8*>(&h2b[16 + (ln & 15)][kk*32 + g8]);
      #pragma unroll
      for (int ci = 0; ci < 6; ++ci){
        int ct = w*6 + ci;
        short8 B = *reinterpret_cast<const short8*>(&g_w3f[((ct*4 + kk)*64 + ln)*8]);
        acc3[ci][0] = __builtin_amdgcn_mfma_f32_16x16x32_bf16(A0, B, acc3[ci][0], 0, 0, 0);
        acc3[ci][1] = __builtin_amdgcn_mfma_f32_16x16x32_bf16(A1, B, acc3[ci][1], 0, 0, 0);
      }
    }
    #pragma unroll
    for (int ci = 0; ci < 6; ++ci){
      float m = acc3[ci][0][0];
      #pragma unroll
      for (int r = 1; r < 4; ++r) m = fmaxf(m, acc3[ci][0][r]);
      #pragma unroll
      for (int r = 0; r < 4; ++r) m = fmaxf(m, acc3[ci][1][r]);
      m = fmaxf(m, __shfl_xor(m, 16));
      m = fmaxf(m, __shfl_xor(m, 32));
      if (ln < 16){
        int col = (w*6 + ci)*16 + ln;
        outPatch[(size_t)bg*DD + col] = m + g_b3[col];
      }
    }
  }
}

// ---------------------------------------------------------------------------
extern "C" void kernel_launch(void* const* d_in, const int* in_sizes, int n_in,
                              void* d_out, int out_size, void* d_ws, size_t ws_size,
                              hipStream_t stream){
  (void)in_sizes; (void)n_in; (void)out_size; (void)d_ws; (void)ws_size;
  const float* xyz  = (const float*)d_in[0];
  const float* feat = (const float*)d_in[1];
  const float* w1 = (const float*)d_in[2];
  const float* g1 = (const float*)d_in[3];
  const float* b1 = (const float*)d_in[4];
  const float* m1 = (const float*)d_in[5];
  const float* v1 = (const float*)d_in[6];
  const float* w2 = (const float*)d_in[7];
  const float* g2 = (const float*)d_in[8];
  const float* b2 = (const float*)d_in[9];
  const float* m2 = (const float*)d_in[10];
  const float* v2 = (const float*)d_in[11];
  const float* w3 = (const float*)d_in[12];
  const float* g3 = (const float*)d_in[13];
  const float* b3 = (const float*)d_in[14];
  const float* m3 = (const float*)d_in[15];
  const float* v3 = (const float*)d_in[16];
  float* out = (float*)d_out;

  k_prep<<<64, 256, 0, stream>>>(w1,g1,b1,m1,v1, w2,g2,b2,m2,v2, w3,g3,b3,m3,v3);
  k_soa<<<(BB*NN)/256, 256, 0, stream>>>(xyz);
  k_zero<<<64, 256, 0, stream>>>();
  k_fps<<<BB*FPS_NBLK, 256, 0, stream>>>(out);
  k_knn<<<BB*GG, 256, 0, stream>>>();
  k_mlp<<<BB*GG, 256, 0, stream>>>(xyz, feat, out + (size_t)BB*GG*3);
}